// Round 9
// baseline (18902.698 us; speedup 1.0000x reference)
//
#include <hip/hip_runtime.h>
#include <stdint.h>

// ---------------------------------------------------------------------------
// LEM-style noisy RNN. T=128 x DIV=10 sequential steps, B=256, H=256.
// Round 9: latency-first restructure. 16 batch-groups x ONE 1024-thread main
// WG (z- and y-updates in the SAME WG -> former L3 hops become barriers) +
// 2 helper WGs/group computing the dt1/i_z panels off the critical path
// (fed y_pre via L3; result consumed one phase later, inside the slack).
// E2 = Wic + Wh fusion and HN = Wh@ny precompute kept from round 8.
// ---------------------------------------------------------------------------

typedef __attribute__((ext_vector_type(8))) short bf16x8_t;
typedef __attribute__((ext_vector_type(4))) float f32x4_t;
typedef unsigned short u16;

__device__ __forceinline__ float bf2f(u16 b) {
  union { uint32_t u; float f; } v; v.u = ((uint32_t)b) << 16; return v.f;
}
__device__ __forceinline__ u16 f2bf(float f) {
  union { float f; uint32_t u; } v; v.f = f;
  uint32_t x = v.u;
  return (u16)((x + 0x7FFFu + ((x >> 16) & 1u)) >> 16);   // RNE
}
__device__ __forceinline__ f32x4_t mfma16(bf16x8_t a, bf16x8_t b, f32x4_t c) {
  return __builtin_amdgcn_mfma_f32_16x16x32_bf16(a, b, c, 0, 0, 0);
}
__device__ __forceinline__ float sigm(float x) { return 1.0f / (1.0f + __expf(-x)); }
__device__ __forceinline__ float tanh_f(float x) {
  float t = __expf(-2.0f * fabsf(x));
  float r = (1.0f - t) / (1.0f + t);
  return x < 0.0f ? -r : r;
}

// ---- L3-coherent (cross-XCD) transport: sc0 sc1 = bypass L1+L2 ----
__device__ __forceinline__ uint2 cload8v(const void* p) {
  uint2 r;
  asm volatile("global_load_dwordx2 %0, %1, off sc0 sc1\n\ts_waitcnt vmcnt(0)"
               : "=&v"(r) : "v"(p) : "memory");
  return r;
}
__device__ __forceinline__ f32x4_t cload16f(const void* p) {
  f32x4_t r;
  asm volatile("global_load_dwordx4 %0, %1, off sc0 sc1\n\ts_waitcnt vmcnt(0)"
               : "=&v"(r) : "v"(p) : "memory");
  return r;
}
__device__ __forceinline__ uint32_t cload4(const void* p) {
  uint32_t r;
  asm volatile("global_load_dword %0, %1, off sc0 sc1\n\ts_waitcnt vmcnt(0)"
               : "=&v"(r) : "v"(p) : "memory");
  return r;
}
__device__ __forceinline__ void cstore8(void* p, uint2 v) {
  asm volatile("global_store_dwordx2 %0, %1, off sc0 sc1" :: "v"(p), "v"(v) : "memory");
}
__device__ __forceinline__ void cstore16f(void* p, f32x4_t v) {
  asm volatile("global_store_dwordx4 %0, %1, off sc0 sc1" :: "v"(p), "v"(v) : "memory");
}
__device__ __forceinline__ void cstore4(void* p, uint32_t v) {
  asm volatile("global_store_dword %0, %1, off sc0 sc1" :: "v"(p), "v"(v) : "memory");
}
__device__ __forceinline__ void vdrain() { asm volatile("s_waitcnt vmcnt(0)" ::: "memory"); }

// MFMA 16x16x32 bf16 A-frag K-position for lane l, elem e
__device__ __forceinline__ int fragK(int l, int e) {
  return ((l >> 4) << 2) + (e & 3) + ((e >> 2) << 4);
}

// ---- JAX threefry2x32 (20 rounds) ----
__device__ __forceinline__ void threefry(uint32_t k0, uint32_t k1, uint32_t x0, uint32_t x1,
                                         uint32_t* o0, uint32_t* o1) {
  uint32_t ks2 = k0 ^ k1 ^ 0x1BD11BDAu;
  x0 += k0; x1 += k1;
#define TFR(rot) { x0 += x1; x1 = (x1 << rot) | (x1 >> (32 - rot)); x1 ^= x0; }
  TFR(13) TFR(15) TFR(26) TFR(6)   x0 += k1;  x1 += ks2 + 1u;
  TFR(17) TFR(29) TFR(16) TFR(24)  x0 += ks2; x1 += k0 + 2u;
  TFR(13) TFR(15) TFR(26) TFR(6)   x0 += k0;  x1 += k1 + 3u;
  TFR(17) TFR(29) TFR(16) TFR(24)  x0 += k1;  x1 += ks2 + 4u;
  TFR(13) TFR(15) TFR(26) TFR(6)   x0 += ks2; x1 += k0 + 5u;
#undef TFR
  *o0 = x0; *o1 = x1;
}

// bits -> N(0,1), matches jax.random.normal f32 (XLA erfinv poly)
__device__ __forceinline__ float bits2normal(uint32_t bits) {
  union { uint32_t u; float f; } cv; cv.u = 0x3F800000u | (bits >> 9);
  float f = cv.f - 1.0f;
  float u = fmaf(f, 2.0f, -0.99999994f);
  u = fmaxf(u, -0.99999994f);
  float w = -log1pf(-u * u);
  float p;
  if (w < 5.0f) {
    w = w - 2.5f;
    p = 2.81022636e-08f;
    p = fmaf(p, w, 3.43273939e-07f);
    p = fmaf(p, w, -3.5233877e-06f);
    p = fmaf(p, w, -4.39150654e-06f);
    p = fmaf(p, w, 0.00021858087f);
    p = fmaf(p, w, -0.00125372503f);
    p = fmaf(p, w, -0.00417768164f);
    p = fmaf(p, w, 0.246640727f);
    p = fmaf(p, w, 1.50140941f);
  } else {
    w = sqrtf(w) - 3.0f;
    p = -0.000200214257f;
    p = fmaf(p, w, 0.000100950558f);
    p = fmaf(p, w, 0.00134934322f);
    p = fmaf(p, w, -0.00367342844f);
    p = fmaf(p, w, 0.00573950773f);
    p = fmaf(p, w, -0.0076224613f);
    p = fmaf(p, w, 0.00943887047f);
    p = fmaf(p, w, 1.00167406f);
    p = fmaf(p, w, 2.83297682f);
  }
  return 1.41421354f * p * u;
}

// ---------------------------------------------------------------------------
__global__ void k_prep(const float* __restrict__ W_i, const float* __restrict__ W_c,
                       const float* __restrict__ b_i, const float* __restrict__ b_c,
                       float* __restrict__ Wic, float* __restrict__ bip) {
  __shared__ float wi[256];
  __shared__ float red[256];
  int o = blockIdx.x; int tid = threadIdx.x;
  wi[tid] = W_i[o * 256 + tid];
  __syncthreads();
  float acc = 0.f;
  for (int j = 0; j < 256; ++j) acc = fmaf(wi[j], W_c[j * 256 + tid], acc);
  Wic[(size_t)o * 256 + tid] = acc;
  red[tid] = wi[tid] * b_c[tid];
  __syncthreads();
  for (int s = 128; s > 0; s >>= 1) { if (tid < s) red[tid] += red[tid + s]; __syncthreads(); }
  if (tid == 0) bip[o] = b_i[o] + red[0];
}

__global__ void k_bias(const float* __restrict__ b_i, const float* __restrict__ bip,
                       const float* __restrict__ b_h,
                       float* __restrict__ biasD0, float* __restrict__ biasDn) {
  int c = blockIdx.x * 256 + threadIdx.x;
  float bh = (c < 512) ? b_h[c] : (c >= 768 ? b_h[c - 256] : 0.f);
  biasD0[c] = b_i[c] + bh;
  biasDn[c] = bip[c] + bh;
}

__global__ void k_packw(const float* __restrict__ srcA, int rowsA, const float* __restrict__ srcB,
                        u16* __restrict__ dst, int O, int K) {
  int t = blockIdx.x * blockDim.x + threadIdx.x;
  int KK = K >> 5;
  int total = (O >> 4) * KK * 64;
  if (t >= total) return;
  int l = t & 63; int kk = (t >> 6) % KK; int to = t / (64 * KK);
  int n = (to << 4) | (l & 15);
  int kb = (kk << 5) + ((l >> 4) << 2);
  const float* src = (n < rowsA) ? (srcA + (size_t)n * K) : (srcB + (size_t)(n - rowsA) * K);
  u16 out[8];
#pragma unroll
  for (int e = 0; e < 8; ++e) out[e] = f2bf(src[kb + (e & 3) + ((e >> 2) << 4)]);
  *reinterpret_cast<uint4*>(dst + (size_t)t * 8) = *reinterpret_cast<const uint4*>(out);
}

// E2 = Wic + Wh aligned (cols 0..511 -> Wh[c], 768..1023 -> Wh[c-256]), 64 tiles
__global__ void k_packe2(const float* __restrict__ Wic, const float* __restrict__ Wh,
                         u16* __restrict__ dst) {
  int t = blockIdx.x * blockDim.x + threadIdx.x;   // 64*8*64 = 32768
  int l = t & 63; int kk = (t >> 6) & 7; int to = t >> 9;
  int n = (to << 4) | (l & 15);
  int kb = (kk << 5) + ((l >> 4) << 2);
  u16 out[8];
#pragma unroll
  for (int e = 0; e < 8; ++e) {
    int k = kb + (e & 3) + ((e >> 2) << 4);
    float v = Wic[(size_t)n * 256 + k];
    if (n < 512) v += Wh[(size_t)n * 256 + k];
    else if (n >= 768) v += Wh[(size_t)(n - 256) * 256 + k];
    out[e] = f2bf(v);
  }
  *reinterpret_cast<uint4*>(dst + (size_t)t * 8) = *reinterpret_cast<const uint4*>(out);
}

__global__ void k_packa(const float* __restrict__ inp, int t0, int Tcc, u16* __restrict__ dst) {
  int t = blockIdx.x * blockDim.x + threadIdx.x;
  int total = Tcc * 16 * 8 * 64;
  if (t >= total) return;
  int l = t & 63; int kk = (t >> 6) & 7; int mt = (t >> 9) & 15; int tl = t >> 13;
  int b = (mt << 4) | (l & 15);
  int kb = (kk << 5) + ((l >> 4) << 2);
  const float* src = inp + ((size_t)(t0 + tl) * 256 + b) * 256;
  u16 out[8];
#pragma unroll
  for (int e = 0; e < 8; ++e) out[e] = f2bf(src[kb + (e & 3) + ((e >> 2) << 4)]);
  *reinterpret_cast<uint4*>(dst + (size_t)t * 8) = *reinterpret_cast<const uint4*>(out);
}

// noise gen; slot sl = global noise step gstep0+sl (gstep0 = t0*10-1)
__global__ void k_gen(u16* __restrict__ Apack, int gstep0) {
  int sl = blockIdx.x >> 7;
  int tb = (blockIdx.x & 127) * 1024 + threadIdx.x;   // [0, 131072)
  __shared__ uint32_t kf[2];
  if (threadIdx.x == 0) {
    uint32_t o0, o1;
    threefry(0u, 1234u, 0u, (uint32_t)(gstep0 + sl), &o0, &o1);
    kf[0] = o0; kf[1] = o1;
  }
  __syncthreads();
  int e = tb & 7; int l = (tb >> 3) & 63; int kk = (tb >> 9) & 15; int mt = tb >> 13;
  int b = (mt << 4) | (l & 15);
  int c = (kk << 5) + fragK(l, e);
  uint32_t i = (uint32_t)(b * 512 + c);
  uint32_t o0, o1;
  threefry(kf[0], kf[1], 0u, i, &o0, &o1);
  Apack[(size_t)sl * 131072 + tb] = f2bf(bits2normal(o0 ^ o1));
}

// S = tanh(noise @ Ws^T + b_s) -> Sny (C-phase tid order), Snz (B-phase tid
// order), nyA (n<256 in A-frag layout, input for k_hn)
__global__ __launch_bounds__(512) void k_sgemm(const u16* __restrict__ Apack,
                                               const u16* __restrict__ Wspack,
                                               const float* __restrict__ b_s,
                                               u16* __restrict__ Sny, u16* __restrict__ Snz,
                                               u16* __restrict__ nyA) {
  int sl = blockIdx.x; int nq = blockIdx.y;
  int l = threadIdx.x & 63; int wv = threadIdx.x >> 6;
  const u16* Ab = Apack + (size_t)sl * 131072;
#pragma unroll 1
  for (int mtl = 0; mtl < 2; ++mtl) {
    int mt = 2 * wv + mtl;
    bf16x8_t af[16];
#pragma unroll
    for (int kk = 0; kk < 16; ++kk)
      af[kk] = *reinterpret_cast<const bf16x8_t*>(Ab + ((size_t)(mt * 16 + kk) * 64 + l) * 8);
#pragma unroll 1
    for (int ntl = 0; ntl < 8; ++ntl) {
      int nt = nq * 8 + ntl;
      f32x4_t acc = {0.f, 0.f, 0.f, 0.f};
#pragma unroll
      for (int kk = 0; kk < 16; ++kk) {
        bf16x8_t bfr = *reinterpret_cast<const bf16x8_t*>(Wspack + ((size_t)(nt * 16 + kk) * 64 + l) * 8);
        acc = mfma16(af[kk], bfr, acc);
      }
      int n = (nt << 4) | (l & 15);
      float bs = b_s[n];
#pragma unroll
      for (int r = 0; r < 4; ++r) {
        int m = (mt << 4) + ((l >> 4) << 2) + r;
        u16 v = f2bf(tanh_f(acc[r] + bs));
        int g = m >> 4, row = m & 15;
        if (n >= 256) {
          int h = n - 256;
          Snz[(((size_t)sl * 16 + g) * 1024 + (row << 6) + (h >> 2)) * 4 + (h & 3)] = v;
        } else {
          int tidc = (n >> 4) * 64 + (((row >> 2) << 4) | (n & 15));
          Sny[(((size_t)sl * 16 + g) * 1024 + tidc) * 4 + (row & 3)] = v;
          int kk2 = n >> 5;
          int la = (((n & 15) >> 2) << 4) | row;
          int ea = (n & 3) | (((n >> 4) & 1) << 2);
          nyA[(((size_t)sl * 16 + g) * 8 + kk2) * 512 + la * 8 + ea] = v;
        }
      }
    }
  }
}

// HN[j] = Wh @ ny(slot j), C/D-frag layout (bf16), 48 col-tiles.
__global__ __launch_bounds__(512) void k_hn(const u16* __restrict__ nyA,
                                            const u16* __restrict__ Epack,
                                            u16* __restrict__ HNpack, int t0) {
  int j = blockIdx.x; int nq = blockIdx.y;
  int l = threadIdx.x & 63; int wv = threadIdx.x >> 6;
  int nt = nq * 8 + wv;                      // [0,48)
  if (j == 0 && t0 == 0) {
    uint2 z = {0u, 0u};
#pragma unroll 1
    for (int mt = 0; mt < 16; ++mt)
      *reinterpret_cast<uint2*>(&HNpack[(((size_t)j * 16 + mt) * 48 + nt) * 256 + l * 4]) = z;
    return;
  }
  bf16x8_t bf[8];
  const u16* bp = Epack + (size_t)(64 + nt) * 4096 + (size_t)l * 8;
#pragma unroll
  for (int kk = 0; kk < 8; ++kk)
    bf[kk] = *reinterpret_cast<const bf16x8_t*>(bp + kk * 512);
#pragma unroll 1
  for (int mt = 0; mt < 16; ++mt) {
    const u16* ap = nyA + (((size_t)j * 16 + mt) * 8) * 512 + (size_t)l * 8;
    f32x4_t acc = {0.f, 0.f, 0.f, 0.f};
#pragma unroll
    for (int kk = 0; kk < 8; ++kk)
      acc = mfma16(*reinterpret_cast<const bf16x8_t*>(ap + kk * 512), bf[kk], acc);
    union { u16 h[4]; uint2 v; } o;
#pragma unroll
    for (int r = 0; r < 4; ++r) o.h[r] = f2bf(acc[r]);
    *reinterpret_cast<uint2*>(&HNpack[(((size_t)j * 16 + mt) * 48 + nt) * 256 + l * 4]) = o.v;
  }
}

// ---------------------------------------------------------------------------
// Recurrence: 48 WGs x 1024 thr. wgid&15 = group g; wgid>>4: 0=main, 1/2=helper.
// Main: A(dt2,iy) -> B(z) -> C(Wz + y) all intra-WG (barriers only).
// Helpers: dt1/i_z panels, fed y_pre via L3, consumed at C (off critical path).
// Flags per group: flg[0],flg[1]=helper done (one line), flg[32]=y published.
__global__ __launch_bounds__(1024) void k_recur(
    const float* __restrict__ dt,
    const u16* __restrict__ Epack, const u16* __restrict__ Wipack, const u16* __restrict__ Wzpack,
    const u16* __restrict__ E2pack, const u16* __restrict__ HNpack,
    const float* __restrict__ biasD0, const float* __restrict__ biasDn,
    const float* __restrict__ b_z, const float* __restrict__ W_dt, const float* __restrict__ b_dt,
    const u16* __restrict__ inpPack, const u16* __restrict__ Sny, const u16* __restrict__ Snz,
    u16* __restrict__ Ypack, float* __restrict__ ystate, float* __restrict__ ypstate,
    float* __restrict__ zstate,
    u16* __restrict__ yexch, float* __restrict__ gexch, int* __restrict__ flags,
    int t0, int Tcc)
{
  __shared__ float Gdt2[16 * 260];
  __shared__ float Giy[16 * 260];
  __shared__ u16 ypb[4096];
  __shared__ u16 axb[4096];
  __shared__ u16 zb[4096];
  __shared__ float sc[48];
  __shared__ float scP[16];

  const int wgid = blockIdx.x;
  const int g = wgid & 15;
  const int role = wgid >> 4;
  const int tid = threadIdx.x;
  const int l = tid & 63;
  const int wv = tid >> 6;               // 0..15
  int* flg = flags + g * 128;
  const int nsteps = Tcc * 10;
  float wdt0 = W_dt[0], wdt1 = W_dt[1], bdt0 = b_dt[0], bdt1 = b_dt[1];

  if (role == 0) {
    // ================= MAIN =================
    const int row = tid >> 6;            // B mapping
    const int hq = (tid & 63) * 4;
    const int ncol = wv * 16 + (l & 15); // C mapping (y col)
    float zc[4], yc[4], ylast[4];
    float bzr = b_z[ncol];
    float bA0d0 = biasD0[(16 + wv) * 16 + (l & 15)], bA0dn = biasDn[(16 + wv) * 16 + (l & 15)];
    float bA1d0 = biasD0[(48 + wv) * 16 + (l & 15)], bA1dn = biasDn[(48 + wv) * 16 + (l & 15)];

    // ---- init ----
#pragma unroll
    for (int j = 0; j < 4; ++j)
      zc[j] = (t0 == 0) ? 0.f : zstate[(size_t)(g * 16 + row) * 256 + hq + j];
#pragma unroll
    for (int r = 0; r < 4; ++r) {
      int m2 = 4 * (l >> 4) + r;
      yc[r] = (t0 == 0) ? 0.f : ystate[(size_t)(g * 16 + m2) * 256 + ncol];
      ylast[r] = 0.f;
    }
    {
      union { u16 h[4]; uint2 v; } pk;
#pragma unroll
      for (int j = 0; j < 4; ++j)
        pk.h[j] = (t0 == 0) ? (u16)0 : f2bf(ypstate[(size_t)(g * 16 + row) * 256 + hq + j]);
      int kk = hq >> 5, e0 = ((hq >> 4) & 1) << 2, ls = (((hq & 15) >> 2) << 4) | row;
      *reinterpret_cast<uint2*>(&ypb[kk * 512 + ls * 8 + e0]) = pk.v;
    }
    __syncthreads();
    cstore8(&yexch[(size_t)g * 4096 + tid * 4], *reinterpret_cast<const uint2*>(&ypb[tid * 4]));
    vdrain();
    __syncthreads();
    if (tid == 0) cstore4(&flg[32], 1u);

    for (int s = 0; s < nsteps; ++s) {
      int d = s % 10, tl = s / 10;
      uint2 snz = *reinterpret_cast<const uint2*>(Snz + (((size_t)(s + 1) * 16 + g) * 1024 + tid) * 4);
      uint2 sny = *reinterpret_cast<const uint2*>(Sny + (((size_t)(s + 1) * 16 + g) * 1024 + tid) * 4);
      if (d == 0) {
        if (tid < 16) {
          float dl = dt[(size_t)(t0 + tl) * 256 + g * 16 + tid] * 0.1f;
          sc[tid] = dl;
          sc[16 + tid] = sigm(fmaf(dl, wdt0, bdt0));
          sc[32 + tid] = sigm(fmaf(dl, wdt1, bdt1));
          int tp = t0 + tl - 1; if (tp < 0) tp = 0;
          scP[tid] = dt[(size_t)tp * 256 + g * 16 + tid] * 0.1f;
        }
        *reinterpret_cast<uint2*>(&axb[tid * 4]) =
            *reinterpret_cast<const uint2*>(inpPack + (size_t)(tl * 16 + g) * 4096 + tid * 4);
        __syncthreads();
      }
      // ---- Phase A: dt2 (tile 16+wv) and iy (tile 48+wv) ----
      {
        bf16x8_t ay[8];
#pragma unroll
        for (int kk = 0; kk < 8; ++kk) ay[kk] = *reinterpret_cast<const bf16x8_t*>(ypb + kk * 512 + l * 8);
        const size_t HNs = ((size_t)s * 16 + g) * 48;
        float scv[4];
#pragma unroll
        for (int r = 0; r < 4; ++r) scv[r] = (d == 0 ? scP[4 * (l >> 4) + r] : sc[4 * (l >> 4) + r]);
        bf16x8_t ax[8];
        if (d == 0) {
#pragma unroll
          for (int kk = 0; kk < 8; ++kk) ax[kk] = *reinterpret_cast<const bf16x8_t*>(axb + kk * 512 + l * 8);
        }
#pragma unroll
        for (int t = 0; t < 2; ++t) {
          int tile = (t == 0) ? (16 + wv) : (48 + wv);
          int hnt  = (t == 0) ? (16 + wv) : (32 + wv);
          f32x4_t acc = {0.f, 0.f, 0.f, 0.f};
          if (d == 0) {
            const u16* bp = Wipack + (size_t)tile * 4096 + (size_t)l * 8;
            const u16* hp = Epack + (size_t)(64 + hnt) * 4096 + (size_t)l * 8;
#pragma unroll
            for (int kk = 0; kk < 8; ++kk)
              acc = mfma16(ax[kk], *reinterpret_cast<const bf16x8_t*>(bp + kk * 512), acc);
#pragma unroll
            for (int kk = 0; kk < 8; ++kk)
              acc = mfma16(ay[kk], *reinterpret_cast<const bf16x8_t*>(hp + kk * 512), acc);
          } else {
            const u16* bp = E2pack + (size_t)tile * 4096 + (size_t)l * 8;
#pragma unroll
            for (int kk = 0; kk < 8; ++kk)
              acc = mfma16(ay[kk], *reinterpret_cast<const bf16x8_t*>(bp + kk * 512), acc);
          }
          uint2 hv = *reinterpret_cast<const uint2*>(&HNpack[(HNs + hnt) * 256 + l * 4]);
          const u16* hh = (const u16*)&hv;
          float bv = (t == 0) ? (d == 0 ? bA0d0 : bA0dn) : (d == 0 ? bA1d0 : bA1dn);
          float* Gp = (t == 0) ? Gdt2 : Giy;
#pragma unroll
          for (int r = 0; r < 4; ++r)
            Gp[(4 * (l >> 4) + r) * 260 + wv * 16 + (l & 15)] = acc[r] + bv + scv[r] * bf2f(hh[r]);
        }
      }
      __syncthreads();
      // ---- Phase B: z update (carry in regs), zb frags ----
      {
        float dl = sc[row], s2 = sc[32 + row];
        f32x4_t p2 = *reinterpret_cast<const f32x4_t*>(&Gdt2[row * 260 + hq]);
        f32x4_t iy = *reinterpret_cast<const f32x4_t*>(&Giy[row * 260 + hq]);
        const u16* nzp = (const u16*)&snz;
        union { u16 h[4]; uint2 v; } zp;
#pragma unroll
        for (int j = 0; j < 4; ++j) {
          float ms = s2 * sigm(p2[j]);
          float zn = (1.0f - ms) * zc[j] + ms * tanh_f(iy[j]);
          zp.h[j] = f2bf(zn);
          zc[j] = fmaf(bf2f(nzp[j]), dl, zn);
        }
        int kk = hq >> 5, e0 = ((hq >> 4) & 1) << 2, ls = (((hq & 15) >> 2) << 4) | row;
        *reinterpret_cast<uint2*>(&zb[kk * 512 + ls * 8 + e0]) = zp.v;
      }
      __syncthreads();
      // ---- Phase C: Wz MFMA + y update (helper panels via L3) ----
      {
        bf16x8_t zfr[8];
#pragma unroll
        for (int kk = 0; kk < 8; ++kk) zfr[kk] = *reinterpret_cast<const bf16x8_t*>(zb + kk * 512 + l * 8);
        const u16* wzp = Wzpack + (size_t)wv * 4096 + (size_t)l * 8;
        f32x4_t acc = {0.f, 0.f, 0.f, 0.f};
#pragma unroll
        for (int kk = 0; kk < 8; ++kk)
          acc = mfma16(zfr[kk], *reinterpret_cast<const bf16x8_t*>(wzp + kk * 512), acc);
        while (true) {
          uint2 f = cload8v(&flg[0]);
          if ((int)f.x >= s + 1 && (int)f.y >= s + 1) break;
          __builtin_amdgcn_s_sleep(2);
        }
        const float* gx = gexch + (((size_t)(s & 1) * 16 + g) * 2) * 4096;
        f32x4_t gdt1 = cload16f(gx + (size_t)(wv * 64 + l) * 4);
        f32x4_t giz  = cload16f(gx + 4096 + (size_t)(wv * 64 + l) * 4);
        const u16* nyp = (const u16*)&sny;
        bool last = (d == 9);
        if (last) __syncthreads();         // all zfr reads done before zb re-use
#pragma unroll
        for (int r = 0; r < 4; ++r) {
          int m2 = 4 * (l >> 4) + r;
          float u = acc[r] + bzr + giz[r];
          float msb = sc[16 + m2] * sigm(gdt1[r]);
          float yn = (1.0f - msb) * yc[r] + msb * tanh_f(u);
          float ypn = fmaf(bf2f(nyp[r]), sc[m2], yn);
          yc[r] = ypn; ylast[r] = yn;
          int kky = ncol >> 5, lsy = (((ncol & 15) >> 2) << 4) | m2;
          int ey = (ncol & 3) | (((ncol >> 4) & 1) << 2);
          int off = kky * 512 + lsy * 8 + ey;
          ypb[off] = f2bf(yn);
          if (last) zb[off] = f2bf(ypn);
        }
      }
      __syncthreads();
      // ---- publish y_pre (contiguous), Ypack at d==9 ----
      cstore8(&yexch[((size_t)((s + 1) & 1) * 16 + g) * 4096 + tid * 4],
              *reinterpret_cast<const uint2*>(&ypb[tid * 4]));
      if (d == 9)
        *reinterpret_cast<uint2*>(Ypack + (size_t)(tl * 16 + g) * 4096 + tid * 4) =
            *reinterpret_cast<const uint2*>(&zb[tid * 4]);
      vdrain();
      __syncthreads();
      if (tid == 0) cstore4(&flg[32], (uint32_t)(s + 2));
    }
    // ---- store carries ----
#pragma unroll
    for (int j = 0; j < 4; ++j) zstate[(size_t)(g * 16 + row) * 256 + hq + j] = zc[j];
#pragma unroll
    for (int r = 0; r < 4; ++r) {
      int m2 = 4 * (l >> 4) + r;
      ystate[(size_t)(g * 16 + m2) * 256 + ncol] = yc[r];
      ypstate[(size_t)(g * 16 + m2) * 256 + ncol] = ylast[r];
    }
  } else {
    // ================= HELPER =================
    const int h = role - 1;
    const bool isDt1 = (wv < 8);
    const int ct = isDt1 ? (h * 8 + wv) : (32 + h * 8 + (wv - 8));  // E2/Wi tile
    const int gslot = isDt1 ? (h * 8 + wv) : (h * 8 + (wv - 8));    // consumer wv
    float b_d0 = biasD0[ct * 16 + (l & 15)];
    float b_dn = biasDn[ct * 16 + (l & 15)];
    for (int s = 0; s < nsteps; ++s) {
      int d = s % 10, tl = s / 10;
      if (d == 0 && tid < 16) {
        float dl = dt[(size_t)(t0 + tl) * 256 + g * 16 + tid] * 0.1f;
        sc[tid] = dl;
        int tp = t0 + tl - 1; if (tp < 0) tp = 0;
        scP[tid] = dt[(size_t)tp * 256 + g * 16 + tid] * 0.1f;
      }
      while ((int)cload4(&flg[32]) < s + 1) __builtin_amdgcn_s_sleep(2);
      {
        uint2 yv = cload8v(yexch + ((size_t)(s & 1) * 16 + g) * 4096 + tid * 4);
        *reinterpret_cast<uint2*>(&ypb[tid * 4]) = yv;
        if (d == 0)
          *reinterpret_cast<uint2*>(&axb[tid * 4]) =
              *reinterpret_cast<const uint2*>(inpPack + (size_t)(tl * 16 + g) * 4096 + tid * 4);
      }
      __syncthreads();
      bf16x8_t ay[8];
#pragma unroll
      for (int kk = 0; kk < 8; ++kk) ay[kk] = *reinterpret_cast<const bf16x8_t*>(ypb + kk * 512 + l * 8);
      f32x4_t acc = {0.f, 0.f, 0.f, 0.f};
      if (d == 0) {
        bf16x8_t ax[8];
#pragma unroll
        for (int kk = 0; kk < 8; ++kk) ax[kk] = *reinterpret_cast<const bf16x8_t*>(axb + kk * 512 + l * 8);
        const u16* bp = Wipack + (size_t)ct * 4096 + (size_t)l * 8;
#pragma unroll
        for (int kk = 0; kk < 8; ++kk)
          acc = mfma16(ax[kk], *reinterpret_cast<const bf16x8_t*>(bp + kk * 512), acc);
        if (isDt1) {
          const u16* hp = Epack + (size_t)(64 + ct) * 4096 + (size_t)l * 8;
#pragma unroll
          for (int kk = 0; kk < 8; ++kk)
            acc = mfma16(ay[kk], *reinterpret_cast<const bf16x8_t*>(hp + kk * 512), acc);
        }
      } else {
        const u16* bp = E2pack + (size_t)ct * 4096 + (size_t)l * 8;
#pragma unroll
        for (int kk = 0; kk < 8; ++kk)
          acc = mfma16(ay[kk], *reinterpret_cast<const bf16x8_t*>(bp + kk * 512), acc);
      }
      f32x4_t outv;
      if (isDt1) {
        uint2 hv = *reinterpret_cast<const uint2*>(
            &HNpack[(((size_t)s * 16 + g) * 48 + ct) * 256 + l * 4]);
        const u16* hh = (const u16*)&hv;
#pragma unroll
        for (int r = 0; r < 4; ++r) {
          float scv = (d == 0 ? scP[4 * (l >> 4) + r] : sc[4 * (l >> 4) + r]);
          outv[r] = acc[r] + (d == 0 ? b_d0 : b_dn) + scv * bf2f(hh[r]);
        }
      } else {
#pragma unroll
        for (int r = 0; r < 4; ++r) outv[r] = acc[r] + (d == 0 ? b_d0 : b_dn);
      }
      float* gx = gexch + (((size_t)(s & 1) * 16 + g) * 2 + (isDt1 ? 0 : 1)) * 4096;
      cstore16f(gx + (size_t)(gslot * 64 + l) * 4, outv);
      vdrain();
      __syncthreads();
      if (tid == 0) cstore4(&flg[h], (uint32_t)(s + 1));
    }
  }
}

// out[t] = Y[t] @ W_c^T + b_c
__global__ __launch_bounds__(512) void k_out(const u16* __restrict__ Ypack, const u16* __restrict__ Wcpack,
                                             const float* __restrict__ b_c, float* __restrict__ out, int t0) {
  int tl = blockIdx.x; int mh = blockIdx.y;
  int l = threadIdx.x & 63; int wv = threadIdx.x >> 6;
  int mt = mh * 8 + wv;
  const u16* Ab = Ypack + (size_t)(tl * 16 + mt) * 4096 + (size_t)l * 8;
  bf16x8_t af[8];
#pragma unroll
  for (int kk = 0; kk < 8; ++kk) af[kk] = *reinterpret_cast<const bf16x8_t*>(Ab + kk * 512);
#pragma unroll 1
  for (int nt = 0; nt < 16; ++nt) {
    f32x4_t acc = {0.f, 0.f, 0.f, 0.f};
    const u16* bp = Wcpack + ((size_t)nt * 8 * 64 + l) * 8;
#pragma unroll
    for (int kk = 0; kk < 8; ++kk) {
      bf16x8_t bfr = *reinterpret_cast<const bf16x8_t*>(bp + kk * 512);
      acc = mfma16(af[kk], bfr, acc);
    }
    int n = (nt << 4) | (l & 15);
    float bc = b_c[n];
#pragma unroll
    for (int r = 0; r < 4; ++r) {
      int m = (mt << 4) + ((l >> 4) << 2) + r;
      out[((size_t)(t0 + tl) * 256 + m) * 256 + n] = acc[r] + bc;
    }
  }
}

// ---------------------------------------------------------------------------
extern "C" void kernel_launch(void* const* d_in, const int* in_sizes, int n_in,
                              void* d_out, int out_size, void* d_ws, size_t ws_size,
                              hipStream_t stream) {
  const float* input = (const float*)d_in[0];
  const float* dt    = (const float*)d_in[1];
  const float* W_i   = (const float*)d_in[2];
  const float* b_i   = (const float*)d_in[3];
  const float* W_h   = (const float*)d_in[4];
  const float* b_h   = (const float*)d_in[5];
  const float* W_z   = (const float*)d_in[6];
  const float* b_z   = (const float*)d_in[7];
  const float* W_dt  = (const float*)d_in[8];
  const float* b_dt  = (const float*)d_in[9];
  const float* W_c   = (const float*)d_in[10];
  const float* b_c   = (const float*)d_in[11];
  const float* W_s   = (const float*)d_in[12];
  const float* b_s   = (const float*)d_in[13];
  float* out = (float*)d_out;

  char* ws = (char*)d_ws;
  size_t off = 0;
  auto alloc = [&](size_t bytes) -> char* {
    char* p = ws + off; off = (off + bytes + 255) & ~(size_t)255; return p;
  };
  u16* Epack   = (u16*)alloc((size_t)112 * 4096 * 2);
  u16* Wipack  = (u16*)alloc((size_t)64 * 4096 * 2);
  u16* Wzpack  = (u16*)alloc((size_t)16 * 4096 * 2);
  u16* Wcpack  = (u16*)alloc((size_t)16 * 4096 * 2);
  u16* Wspack  = (u16*)alloc((size_t)32 * 16 * 512 * 2);
  u16* E2pack  = (u16*)alloc((size_t)64 * 4096 * 2);
  float* bip   = (float*)alloc(1024 * 4);
  float* biasD0= (float*)alloc(1024 * 4);
  float* biasDn= (float*)alloc(1024 * 4);
  float* Wic   = (float*)alloc((size_t)1024 * 256 * 4);
  float* ystate= (float*)alloc((size_t)256 * 256 * 4);
  float* ypstate=(float*)alloc((size_t)256 * 256 * 4);
  float* zstate= (float*)alloc((size_t)256 * 256 * 4);
  u16* yexch   = (u16*)alloc((size_t)2 * 16 * 4096 * 2);
  float* gexch = (float*)alloc((size_t)2 * 16 * 2 * 4096 * 4);
  int* flags   = (int*)alloc((size_t)16 * 128 * 4);
  size_t fixed = off;
  size_t per_slot = (size_t)131072 * 2 + 65536 * 2 + 65536 * 2 + 65536 * 2;
  size_t per_t = 10 * per_slot + (size_t)10 * 196608 * 2 + 131072 + 131072;
  int Tc = 1;
  if (ws_size > fixed + per_t + per_slot) {
    size_t n = (ws_size - fixed - per_slot) / per_t;
    Tc = (n > 128) ? 128 : (int)n;
  }
  if (Tc < 1) Tc = 1;
  int maxslots = Tc * 10 + 1;
  u16* Apack   = (u16*)alloc((size_t)maxslots * 131072 * 2);
  u16* Sny     = (u16*)alloc((size_t)maxslots * 65536 * 2);
  u16* Snz     = (u16*)alloc((size_t)maxslots * 65536 * 2);
  u16* nyA     = (u16*)alloc((size_t)maxslots * 65536 * 2);
  u16* HNpack  = (u16*)alloc((size_t)(Tc * 10) * 196608 * 2);
  u16* inpPack = (u16*)alloc((size_t)Tc * 16 * 8 * 512 * 2);
  u16* Ypack   = (u16*)alloc((size_t)Tc * 16 * 8 * 512 * 2);

  k_prep<<<1024, 256, 0, stream>>>(W_i, W_c, b_i, b_c, Wic, bip);
  k_bias<<<4, 256, 0, stream>>>(b_i, bip, b_h, biasD0, biasDn);
  k_packw<<<(112 * 8 * 64) / 256, 256, 0, stream>>>(Wic, 1024, W_h, Epack, 1792, 256);
  k_packw<<<(64 * 8 * 64) / 256, 256, 0, stream>>>(W_i, 1024, (const float*)nullptr, Wipack, 1024, 256);
  k_packw<<<(16 * 8 * 64) / 256, 256, 0, stream>>>(W_z, 256, (const float*)nullptr, Wzpack, 256, 256);
  k_packw<<<(16 * 8 * 64) / 256, 256, 0, stream>>>(W_c, 256, (const float*)nullptr, Wcpack, 256, 256);
  k_packw<<<(32 * 16 * 64) / 256, 256, 0, stream>>>(W_s, 512, (const float*)nullptr, Wspack, 512, 512);
  k_packe2<<<128, 256, 0, stream>>>(Wic, W_h, E2pack);

  for (int t0 = 0; t0 < 128; t0 += Tc) {
    int Tcc = (128 - t0 < Tc) ? (128 - t0) : Tc;
    int nsteps = Tcc * 10;
    int slots = nsteps + 1;
    k_gen<<<slots * 128, 1024, 0, stream>>>(Apack, t0 * 10 - 1);
    dim3 g2(slots, 4);
    k_sgemm<<<g2, 512, 0, stream>>>(Apack, Wspack, b_s, Sny, Snz, nyA);
    dim3 g3(nsteps, 6);
    k_hn<<<g3, 512, 0, stream>>>(nyA, Epack, HNpack, t0);
    int totalA = Tcc * 16 * 8 * 64;
    k_packa<<<(totalA + 255) / 256, 256, 0, stream>>>(input, t0, Tcc, inpPack);
    hipMemsetAsync(flags, 0, 16 * 128 * 4, stream);
    k_recur<<<48, 1024, 0, stream>>>(dt, Epack, Wipack, Wzpack, E2pack, HNpack,
                                     biasD0, biasDn, b_z, W_dt, b_dt, inpPack, Sny, Snz,
                                     Ypack, ystate, ypstate, zstate, yexch, gexch, flags, t0, Tcc);
    dim3 ge(Tcc, 2);
    k_out<<<ge, 512, 0, stream>>>(Ypack, Wcpack, b_c, out, t0);
  }
}

// Round 10
// 8908.169 us; speedup vs baseline: 2.1220x; 2.1220x over previous
//
#include <hip/hip_runtime.h>
#include <stdint.h>

// ---------------------------------------------------------------------------
// LEM-style noisy RNN. T=128 x DIV=10 sequential steps, B=256, H=256.
// Round 10: 16 groups x 4 WGs (Y0,Y1,Z0,Z1), 512 thr each.
//  - Each WG's 16 E2 weight tiles (128KB) PRELOADED INTO LDS (was the L1
//    stream bottleneck); Wz register-resident on Y side (32 VGPR).
//  - Each wave computes BOTH panels of one column tile -> A-phase results
//    stay in registers with the exact (row,col) mapping B/C need: no G
//    exchange, no extra barriers.
//  - Cross-WG y/z via L3-coherent sc0sc1 transport (rounds 6-8 scheme).
//  - E2 = Wic+Wh fusion, HN = Wh@ny precompute (round 8).
// ---------------------------------------------------------------------------

typedef __attribute__((ext_vector_type(8))) short bf16x8_t;
typedef __attribute__((ext_vector_type(4))) float f32x4_t;
typedef unsigned short u16;

#define R_LDS_BYTES 155904

__device__ __forceinline__ float bf2f(u16 b) {
  union { uint32_t u; float f; } v; v.u = ((uint32_t)b) << 16; return v.f;
}
__device__ __forceinline__ u16 f2bf(float f) {
  union { float f; uint32_t u; } v; v.f = f;
  uint32_t x = v.u;
  return (u16)((x + 0x7FFFu + ((x >> 16) & 1u)) >> 16);   // RNE
}
__device__ __forceinline__ f32x4_t mfma16(bf16x8_t a, bf16x8_t b, f32x4_t c) {
  return __builtin_amdgcn_mfma_f32_16x16x32_bf16(a, b, c, 0, 0, 0);
}
__device__ __forceinline__ float sigm(float x) { return 1.0f / (1.0f + __expf(-x)); }
__device__ __forceinline__ float tanh_f(float x) {
  float t = __expf(-2.0f * fabsf(x));
  float r = (1.0f - t) / (1.0f + t);
  return x < 0.0f ? -r : r;
}

// ---- L3-coherent (cross-XCD) transport: sc0 sc1 = bypass L1+L2 ----
__device__ __forceinline__ uint4 cload16(const void* p) {
  uint4 r;
  asm volatile("global_load_dwordx4 %0, %1, off sc0 sc1\n\ts_waitcnt vmcnt(0)"
               : "=&v"(r) : "v"(p) : "memory");
  return r;
}
__device__ __forceinline__ void cstore8(void* p, uint2 v) {
  asm volatile("global_store_dwordx2 %0, %1, off sc0 sc1" :: "v"(p), "v"(v) : "memory");
}
__device__ __forceinline__ void cstore4(void* p, uint32_t v) {
  asm volatile("global_store_dword %0, %1, off sc0 sc1" :: "v"(p), "v"(v) : "memory");
}
__device__ __forceinline__ void vdrain() { asm volatile("s_waitcnt vmcnt(0)" ::: "memory"); }
__device__ __forceinline__ void poll2(const int* p0, const int* p1, int target) {
  while (true) {
    uint32_t a, b;
    asm volatile("global_load_dword %0, %2, off sc0 sc1\n\t"
                 "global_load_dword %1, %3, off sc0 sc1\n\t"
                 "s_waitcnt vmcnt(0)"
                 : "=&v"(a), "=&v"(b) : "v"(p0), "v"(p1) : "memory");
    if ((int)a >= target && (int)b >= target) return;
    __builtin_amdgcn_s_sleep(2);
  }
}

// MFMA 16x16x32 bf16 A-frag K-position for lane l, elem e
__device__ __forceinline__ int fragK(int l, int e) {
  return ((l >> 4) << 2) + (e & 3) + ((e >> 2) << 4);
}
// A-frag local slot (within a 2048-u16 half) for row m, col h (h local 0..127 + half*128)
__device__ __forceinline__ int halfSlot(int h, int m) {
  return ((h >> 5) & 3) * 512 + (((((h & 15) >> 2) << 4) | m) << 3) +
         ((h & 3) | (((h >> 4) & 1) << 2));
}

// ---- JAX threefry2x32 (20 rounds) ----
__device__ __forceinline__ void threefry(uint32_t k0, uint32_t k1, uint32_t x0, uint32_t x1,
                                         uint32_t* o0, uint32_t* o1) {
  uint32_t ks2 = k0 ^ k1 ^ 0x1BD11BDAu;
  x0 += k0; x1 += k1;
#define TFR(rot) { x0 += x1; x1 = (x1 << rot) | (x1 >> (32 - rot)); x1 ^= x0; }
  TFR(13) TFR(15) TFR(26) TFR(6)   x0 += k1;  x1 += ks2 + 1u;
  TFR(17) TFR(29) TFR(16) TFR(24)  x0 += ks2; x1 += k0 + 2u;
  TFR(13) TFR(15) TFR(26) TFR(6)   x0 += k0;  x1 += k1 + 3u;
  TFR(17) TFR(29) TFR(16) TFR(24)  x0 += k1;  x1 += ks2 + 4u;
  TFR(13) TFR(15) TFR(26) TFR(6)   x0 += ks2; x1 += k0 + 5u;
#undef TFR
  *o0 = x0; *o1 = x1;
}

// bits -> N(0,1), matches jax.random.normal f32 (XLA erfinv poly)
__device__ __forceinline__ float bits2normal(uint32_t bits) {
  union { uint32_t u; float f; } cv; cv.u = 0x3F800000u | (bits >> 9);
  float f = cv.f - 1.0f;
  float u = fmaf(f, 2.0f, -0.99999994f);
  u = fmaxf(u, -0.99999994f);
  float w = -log1pf(-u * u);
  float p;
  if (w < 5.0f) {
    w = w - 2.5f;
    p = 2.81022636e-08f;
    p = fmaf(p, w, 3.43273939e-07f);
    p = fmaf(p, w, -3.5233877e-06f);
    p = fmaf(p, w, -4.39150654e-06f);
    p = fmaf(p, w, 0.00021858087f);
    p = fmaf(p, w, -0.00125372503f);
    p = fmaf(p, w, -0.00417768164f);
    p = fmaf(p, w, 0.246640727f);
    p = fmaf(p, w, 1.50140941f);
  } else {
    w = sqrtf(w) - 3.0f;
    p = -0.000200214257f;
    p = fmaf(p, w, 0.000100950558f);
    p = fmaf(p, w, 0.00134934322f);
    p = fmaf(p, w, -0.00367342844f);
    p = fmaf(p, w, 0.00573950773f);
    p = fmaf(p, w, -0.0076224613f);
    p = fmaf(p, w, 0.00943887047f);
    p = fmaf(p, w, 1.00167406f);
    p = fmaf(p, w, 2.83297682f);
  }
  return 1.41421354f * p * u;
}

// ---------------------------------------------------------------------------
__global__ void k_prep(const float* __restrict__ W_i, const float* __restrict__ W_c,
                       const float* __restrict__ b_i, const float* __restrict__ b_c,
                       float* __restrict__ Wic, float* __restrict__ bip) {
  __shared__ float wi[256];
  __shared__ float red[256];
  int o = blockIdx.x; int tid = threadIdx.x;
  wi[tid] = W_i[o * 256 + tid];
  __syncthreads();
  float acc = 0.f;
  for (int j = 0; j < 256; ++j) acc = fmaf(wi[j], W_c[j * 256 + tid], acc);
  Wic[(size_t)o * 256 + tid] = acc;
  red[tid] = wi[tid] * b_c[tid];
  __syncthreads();
  for (int s = 128; s > 0; s >>= 1) { if (tid < s) red[tid] += red[tid + s]; __syncthreads(); }
  if (tid == 0) bip[o] = b_i[o] + red[0];
}

__global__ void k_bias(const float* __restrict__ b_i, const float* __restrict__ bip,
                       const float* __restrict__ b_h,
                       float* __restrict__ biasD0, float* __restrict__ biasDn) {
  int c = blockIdx.x * 256 + threadIdx.x;
  float bh = (c < 512) ? b_h[c] : (c >= 768 ? b_h[c - 256] : 0.f);
  biasD0[c] = b_i[c] + bh;
  biasDn[c] = bip[c] + bh;
}

__global__ void k_packw(const float* __restrict__ srcA, int rowsA, const float* __restrict__ srcB,
                        u16* __restrict__ dst, int O, int K) {
  int t = blockIdx.x * blockDim.x + threadIdx.x;
  int KK = K >> 5;
  int total = (O >> 4) * KK * 64;
  if (t >= total) return;
  int l = t & 63; int kk = (t >> 6) % KK; int to = t / (64 * KK);
  int n = (to << 4) | (l & 15);
  int kb = (kk << 5) + ((l >> 4) << 2);
  const float* src = (n < rowsA) ? (srcA + (size_t)n * K) : (srcB + (size_t)(n - rowsA) * K);
  u16 out[8];
#pragma unroll
  for (int e = 0; e < 8; ++e) out[e] = f2bf(src[kb + (e & 3) + ((e >> 2) << 4)]);
  *reinterpret_cast<uint4*>(dst + (size_t)t * 8) = *reinterpret_cast<const uint4*>(out);
}

// E2 = Wic + Wh aligned (cols 0..511 -> Wh[c], 768..1023 -> Wh[c-256]), 64 tiles
__global__ void k_packe2(const float* __restrict__ Wic, const float* __restrict__ Wh,
                         u16* __restrict__ dst) {
  int t = blockIdx.x * blockDim.x + threadIdx.x;   // 64*8*64 = 32768
  int l = t & 63; int kk = (t >> 6) & 7; int to = t >> 9;
  int n = (to << 4) | (l & 15);
  int kb = (kk << 5) + ((l >> 4) << 2);
  u16 out[8];
#pragma unroll
  for (int e = 0; e < 8; ++e) {
    int k = kb + (e & 3) + ((e >> 2) << 4);
    float v = Wic[(size_t)n * 256 + k];
    if (n < 512) v += Wh[(size_t)n * 256 + k];
    else if (n >= 768) v += Wh[(size_t)(n - 256) * 256 + k];
    out[e] = f2bf(v);
  }
  *reinterpret_cast<uint4*>(dst + (size_t)t * 8) = *reinterpret_cast<const uint4*>(out);
}

__global__ void k_packa(const float* __restrict__ inp, int t0, int Tcc, u16* __restrict__ dst) {
  int t = blockIdx.x * blockDim.x + threadIdx.x;
  int total = Tcc * 16 * 8 * 64;
  if (t >= total) return;
  int l = t & 63; int kk = (t >> 6) & 7; int mt = (t >> 9) & 15; int tl = t >> 13;
  int b = (mt << 4) | (l & 15);
  int kb = (kk << 5) + ((l >> 4) << 2);
  const float* src = inp + ((size_t)(t0 + tl) * 256 + b) * 256;
  u16 out[8];
#pragma unroll
  for (int e = 0; e < 8; ++e) out[e] = f2bf(src[kb + (e & 3) + ((e >> 2) << 4)]);
  *reinterpret_cast<uint4*>(dst + (size_t)t * 8) = *reinterpret_cast<const uint4*>(out);
}

// noise gen; slot sl = global noise step gstep0+sl (gstep0 = t0*10-1)
__global__ void k_gen(u16* __restrict__ Apack, int gstep0) {
  int sl = blockIdx.x >> 7;
  int tb = (blockIdx.x & 127) * 1024 + threadIdx.x;   // [0, 131072)
  __shared__ uint32_t kf[2];
  if (threadIdx.x == 0) {
    uint32_t o0, o1;
    threefry(0u, 1234u, 0u, (uint32_t)(gstep0 + sl), &o0, &o1);
    kf[0] = o0; kf[1] = o1;
  }
  __syncthreads();
  int e = tb & 7; int l = (tb >> 3) & 63; int kk = (tb >> 9) & 15; int mt = tb >> 13;
  int b = (mt << 4) | (l & 15);
  int c = (kk << 5) + fragK(l, e);
  uint32_t i = (uint32_t)(b * 512 + c);
  uint32_t o0, o1;
  threefry(kf[0], kf[1], 0u, i, &o0, &o1);
  Apack[(size_t)sl * 131072 + tb] = f2bf(bits2normal(o0 ^ o1));
}

// S = tanh(noise @ Ws^T + b_s) -> Sny/Snz (per (g,half), C/D-row-mapped thread
// order: thread = wv*64 + ((row>>2)<<4) + (col&15), elem = row&3), and nyA
// (n<256 in A-frag layout, input for k_hn).
__global__ __launch_bounds__(512) void k_sgemm(const u16* __restrict__ Apack,
                                               const u16* __restrict__ Wspack,
                                               const float* __restrict__ b_s,
                                               u16* __restrict__ Sny, u16* __restrict__ Snz,
                                               u16* __restrict__ nyA) {
  int sl = blockIdx.x; int nq = blockIdx.y;
  int l = threadIdx.x & 63; int wv = threadIdx.x >> 6;
  const u16* Ab = Apack + (size_t)sl * 131072;
#pragma unroll 1
  for (int mtl = 0; mtl < 2; ++mtl) {
    int mt = 2 * wv + mtl;
    bf16x8_t af[16];
#pragma unroll
    for (int kk = 0; kk < 16; ++kk)
      af[kk] = *reinterpret_cast<const bf16x8_t*>(Ab + ((size_t)(mt * 16 + kk) * 64 + l) * 8);
#pragma unroll 1
    for (int ntl = 0; ntl < 8; ++ntl) {
      int nt = nq * 8 + ntl;
      f32x4_t acc = {0.f, 0.f, 0.f, 0.f};
#pragma unroll
      for (int kk = 0; kk < 16; ++kk) {
        bf16x8_t bfr = *reinterpret_cast<const bf16x8_t*>(Wspack + ((size_t)(nt * 16 + kk) * 64 + l) * 8);
        acc = mfma16(af[kk], bfr, acc);
      }
      int n = (nt << 4) | (l & 15);
      float bs = b_s[n];
#pragma unroll
      for (int r = 0; r < 4; ++r) {
        int m = (mt << 4) + ((l >> 4) << 2) + r;
        u16 v = f2bf(tanh_f(acc[r] + bs));
        int g = m >> 4, row = m & 15;
        if (n >= 256) {
          int h = n - 256; int hz = h >> 7;
          int tidc = ((h >> 4) & 7) * 64 + ((row >> 2) << 4) + (h & 15);
          Snz[((((size_t)sl * 16 + g) * 2 + hz) * 512 + tidc) * 4 + (row & 3)] = v;
        } else {
          int hy = n >> 7;
          int tidc = ((n >> 4) & 7) * 64 + ((row >> 2) << 4) + (n & 15);
          Sny[((((size_t)sl * 16 + g) * 2 + hy) * 512 + tidc) * 4 + (row & 3)] = v;
          int kk2 = n >> 5;
          int la = (((n & 15) >> 2) << 4) | row;
          int ea = (n & 3) | (((n >> 4) & 1) << 2);
          nyA[(((size_t)sl * 16 + g) * 8 + kk2) * 512 + la * 8 + ea] = v;
        }
      }
    }
  }
}

// HN[j] = Wh @ ny(slot j), C/D-frag layout (bf16), 48 col-tiles.
__global__ __launch_bounds__(512) void k_hn(const u16* __restrict__ nyA,
                                            const u16* __restrict__ Epack,
                                            u16* __restrict__ HNpack, int t0) {
  int j = blockIdx.x; int nq = blockIdx.y;
  int l = threadIdx.x & 63; int wv = threadIdx.x >> 6;
  int nt = nq * 8 + wv;                      // [0,48)
  if (j == 0 && t0 == 0) {
    uint2 z = {0u, 0u};
#pragma unroll 1
    for (int mt = 0; mt < 16; ++mt)
      *reinterpret_cast<uint2*>(&HNpack[(((size_t)j * 16 + mt) * 48 + nt) * 256 + l * 4]) = z;
    return;
  }
  bf16x8_t bf[8];
  const u16* bp = Epack + (size_t)(64 + nt) * 4096 + (size_t)l * 8;
#pragma unroll
  for (int kk = 0; kk < 8; ++kk)
    bf[kk] = *reinterpret_cast<const bf16x8_t*>(bp + kk * 512);
#pragma unroll 1
  for (int mt = 0; mt < 16; ++mt) {
    const u16* ap = nyA + (((size_t)j * 16 + mt) * 8) * 512 + (size_t)l * 8;
    f32x4_t acc = {0.f, 0.f, 0.f, 0.f};
#pragma unroll
    for (int kk = 0; kk < 8; ++kk)
      acc = mfma16(*reinterpret_cast<const bf16x8_t*>(ap + kk * 512), bf[kk], acc);
    union { u16 h[4]; uint2 v; } o;
#pragma unroll
    for (int r = 0; r < 4; ++r) o.h[r] = f2bf(acc[r]);
    *reinterpret_cast<uint2*>(&HNpack[(((size_t)j * 16 + mt) * 48 + nt) * 256 + l * 4]) = o.v;
  }
}

// ---------------------------------------------------------------------------
// Recurrence, 64 WGs x 512. wgid = role*16 + g. role 0/1 = Y(hy), 2/3 = Z(hz).
// Flags: flg[0]/flg[32] = y halves; flg[64]/flg[96] = z halves.
__global__ __launch_bounds__(512, 2) void k_recur(
    const float* __restrict__ dt,
    const u16* __restrict__ Epack, const u16* __restrict__ Wipack, const u16* __restrict__ Wzpack,
    const u16* __restrict__ E2pack, const u16* __restrict__ HNpack,
    const float* __restrict__ biasD0, const float* __restrict__ biasDn,
    const float* __restrict__ b_z, const float* __restrict__ W_dt, const float* __restrict__ b_dt,
    const u16* __restrict__ inpPack, const u16* __restrict__ Sny, const u16* __restrict__ Snz,
    u16* __restrict__ Ypack, float* __restrict__ ystate, float* __restrict__ ypstate,
    float* __restrict__ zstate,
    u16* __restrict__ yexch, u16* __restrict__ zexch, int* __restrict__ flags,
    int t0, int Tcc)
{
  extern __shared__ char lds_raw[];
  u16* wlds  = (u16*)lds_raw;                 // [16][4096] E2 tiles (128KB)
  u16* ypb   = wlds + 65536;                  // 4096: y_pre frags
  u16* buf2  = ypb + 4096;                    // 4096: Z: x frags @d0; Y: z frags
  u16* stage = buf2 + 4096;                   // 4096: Z: z-stage[0,2048); Y: x@d0 / y-stage + ypn@d9
  float* sc  = (float*)(stage + 4096);        // 48
  float* scP = sc + 48;                       // 16

  const int wgid = blockIdx.x;
  const int g = wgid & 15;
  const int role = wgid >> 4;
  const bool isY = role < 2;
  const int half = role & 1;
  const int tid = threadIdx.x;
  const int l = tid & 63;
  const int wv = tid >> 6;
  int* flg = flags + g * 128;
  const int nsteps = Tcc * 10;
  const int m2b = 4 * (l >> 4);
  const int col = half * 128 + wv * 16 + (l & 15);   // this thread's output column

  // tile ids
  int wiT0, whT0, hnT0, wiT1, whT1 = -1, hnT1 = -1;
  if (isY) {
    wiT0 = half * 8 + wv;       whT0 = 64 + wiT0;  hnT0 = wiT0;
    wiT1 = 32 + half * 8 + wv;
  } else {
    wiT0 = 16 + half * 8 + wv;  whT0 = 64 + wiT0;  hnT0 = wiT0;
    wiT1 = 48 + half * 8 + wv;  whT1 = 96 + half * 8 + wv;  hnT1 = 32 + half * 8 + wv;
  }
  float b0d0 = biasD0[wiT0 * 16 + (l & 15)], b0dn = biasDn[wiT0 * 16 + (l & 15)];
  float b1d0 = biasD0[wiT1 * 16 + (l & 15)], b1dn = biasDn[wiT1 * 16 + (l & 15)];

  // ---- preload E2 weight tiles into LDS ----
  for (int i = tid; i < 8192; i += 512) {
    int t = i >> 9; int o = (i & 511) << 3;
    int gt;
    if (isY) gt = (t < 8) ? (half * 8 + t) : (32 + half * 8 + (t - 8));
    else     gt = (t < 8) ? (16 + half * 8 + t) : (48 + half * 8 + (t - 8));
    *reinterpret_cast<uint4*>(wlds + t * 4096 + o) =
        *reinterpret_cast<const uint4*>(E2pack + (size_t)gt * 4096 + o);
  }

  float zc[4], yc[4], ylast[4];
  bf16x8_t wzf[8];
  float bzr = 0.f;

  if (isY) {
    bzr = b_z[col];
#pragma unroll
    for (int kk = 0; kk < 8; ++kk)
      wzf[kk] = *reinterpret_cast<const bf16x8_t*>(
          Wzpack + (size_t)(half * 8 + wv) * 4096 + (size_t)kk * 512 + (size_t)l * 8);
#pragma unroll
    for (int r = 0; r < 4; ++r) {
      int m2 = m2b + r;
      yc[r] = (t0 == 0) ? 0.f : ystate[(size_t)(g * 16 + m2) * 256 + col];
      ylast[r] = 0.f;
      float v = (t0 == 0) ? 0.f : ypstate[(size_t)(g * 16 + m2) * 256 + col];
      stage[halfSlot(col, m2)] = f2bf(v);
    }
    __syncthreads();
    cstore8(&yexch[(size_t)g * 4096 + half * 2048 + tid * 4],
            *reinterpret_cast<const uint2*>(&stage[tid * 4]));
    vdrain();
    __syncthreads();
    if (tid == 0) cstore4(&flg[half * 32], 1u);
  } else {
#pragma unroll
    for (int r = 0; r < 4; ++r)
      zc[r] = (t0 == 0) ? 0.f : zstate[(size_t)(g * 16 + m2b + r) * 256 + col];
  }

  float wdt0 = W_dt[0], wdt1 = W_dt[1], bdt0 = b_dt[0], bdt1 = b_dt[1];

  for (int s = 0; s < nsteps; ++s) {
    int d = s % 10, tl = s / 10;
    // prefetch (normal loads; latency hides under the poll)
    const u16* SnX = isY ? Sny : Snz;
    uint2 nsv = *reinterpret_cast<const uint2*>(
        SnX + ((((size_t)(s + 1) * 16 + g) * 2 + half) * 512 + tid) * 4);
    size_t HNs = ((size_t)s * 16 + g) * 48;
    uint2 hv0 = *reinterpret_cast<const uint2*>(HNpack + (HNs + hnT0) * 256 + l * 4);
    uint2 hv1 = {0u, 0u};
    if (!isY) hv1 = *reinterpret_cast<const uint2*>(HNpack + (HNs + hnT1) * 256 + l * 4);
    if (d == 0 && tid < 16) {
      float dl = dt[(size_t)(t0 + tl) * 256 + g * 16 + tid] * 0.1f;
      sc[tid] = dl;
      sc[16 + tid] = sigm(fmaf(dl, wdt0, bdt0));
      sc[32 + tid] = sigm(fmaf(dl, wdt1, bdt1));
      int tp = t0 + tl - 1; if (tp < 0) tp = 0;
      scP[tid] = dt[(size_t)tp * 256 + g * 16 + tid] * 0.1f;
    }
    // ---- wait y(s), load y_pre (+x at d==0) ----
    poll2(&flg[0], &flg[32], s + 1);
    {
      uint4 ry = cload16(yexch + ((size_t)(s & 1) * 16 + g) * 4096 + tid * 8);
      *reinterpret_cast<uint4*>(ypb + tid * 8) = ry;
      if (d == 0) {
        u16* xb = isY ? stage : buf2;
        *reinterpret_cast<uint4*>(xb + tid * 8) =
            *reinterpret_cast<const uint4*>(inpPack + (size_t)(tl * 16 + g) * 4096 + tid * 8);
      }
    }
    __syncthreads();                                    // BAR_a

    // ---- Phase A: both panels of this wave's column tile, in-register ----
    f32x4_t r0, r1;
    {
      bf16x8_t ay[8];
#pragma unroll
      for (int kk = 0; kk < 8; ++kk)
        ay[kk] = *reinterpret_cast<const bf16x8_t*>(ypb + kk * 512 + l * 8);
      float scv[4];
#pragma unroll
      for (int r = 0; r < 4; ++r) scv[r] = (d == 0 ? scP[m2b + r] : sc[m2b + r]);
      f32x4_t a0 = {0.f, 0.f, 0.f, 0.f}, a1 = {0.f, 0.f, 0.f, 0.f};
      if (d == 0) {
        bf16x8_t ax[8];
        const u16* xb = isY ? stage : buf2;
#pragma unroll
        for (int kk = 0; kk < 8; ++kk)
          ax[kk] = *reinterpret_cast<const bf16x8_t*>(xb + kk * 512 + l * 8);
        const u16* bp0 = Wipack + (size_t)wiT0 * 4096 + (size_t)l * 8;
        const u16* hp0 = Epack + (size_t)whT0 * 4096 + (size_t)l * 8;
#pragma unroll
        for (int kk = 0; kk < 8; ++kk)
          a0 = mfma16(ax[kk], *reinterpret_cast<const bf16x8_t*>(bp0 + kk * 512), a0);
#pragma unroll
        for (int kk = 0; kk < 8; ++kk)
          a0 = mfma16(ay[kk], *reinterpret_cast<const bf16x8_t*>(hp0 + kk * 512), a0);
        const u16* bp1 = Wipack + (size_t)wiT1 * 4096 + (size_t)l * 8;
#pragma unroll
        for (int kk = 0; kk < 8; ++kk)
          a1 = mfma16(ax[kk], *reinterpret_cast<const bf16x8_t*>(bp1 + kk * 512), a1);
        if (!isY) {
          const u16* hp1 = Epack + (size_t)whT1 * 4096 + (size_t)l * 8;
#pragma unroll
          for (int kk = 0; kk < 8; ++kk)
            a1 = mfma16(ay[kk], *reinterpret_cast<const bf16x8_t*>(hp1 + kk * 512), a1);
        }
      } else {
        const u16* w0 = wlds + wv * 4096 + l * 8;
        const u16* w1 = wlds + (8 + wv) * 4096 + l * 8;
#pragma unroll
        for (int kk = 0; kk < 8; ++kk)
          a0 = mfma16(ay[kk], *reinterpret_cast<const bf16x8_t*>(w0 + kk * 512), a0);
#pragma unroll
        for (int kk = 0; kk < 8; ++kk)
          a1 = mfma16(ay[kk], *reinterpret_cast<const bf16x8_t*>(w1 + kk * 512), a1);
      }
      const u16* h0 = (const u16*)&hv0;
#pragma unroll
      for (int r = 0; r < 4; ++r)
        r0[r] = a0[r] + (d == 0 ? b0d0 : b0dn) + scv[r] * bf2f(h0[r]);
      if (!isY) {
        const u16* h1 = (const u16*)&hv1;
#pragma unroll
        for (int r = 0; r < 4; ++r)
          r1[r] = a1[r] + (d == 0 ? b1d0 : b1dn) + scv[r] * bf2f(h1[r]);
      } else {
#pragma unroll
        for (int r = 0; r < 4; ++r)
          r1[r] = a1[r] + (d == 0 ? b1d0 : b1dn);
      }
    }

    if (!isY) {
      // ---- Phase B: z update in-register; stage half; publish ----
      const u16* nzp = (const u16*)&nsv;
#pragma unroll
      for (int r = 0; r < 4; ++r) {
        int m2 = m2b + r;
        float ms = sc[32 + m2] * sigm(r0[r]);
        float zn = (1.0f - ms) * zc[r] + ms * tanh_f(r1[r]);
        stage[halfSlot(col, m2)] = f2bf(zn);
        zc[r] = fmaf(bf2f(nzp[r]), sc[m2], zn);
      }
      __syncthreads();                                  // BAR_b
      cstore8(&zexch[((size_t)(s & 1) * 16 + g) * 4096 + half * 2048 + tid * 4],
              *reinterpret_cast<const uint2*>(&stage[tid * 4]));
      vdrain();
      __syncthreads();                                  // BAR_c
      if (tid == 0) cstore4(&flg[(2 + half) * 32], (uint32_t)(s + 1));
    } else {
      // ---- wait z(s), load z frags ----
      poll2(&flg[64], &flg[96], s + 1);
      {
        uint4 rz = cload16(zexch + ((size_t)(s & 1) * 16 + g) * 4096 + tid * 8);
        *reinterpret_cast<uint4*>(buf2 + tid * 8) = rz;
      }
      __syncthreads();                                  // BAR_b
      // ---- Phase C: Wz MFMA (reg weights) + y update in-register ----
      bf16x8_t zfr[8];
#pragma unroll
      for (int kk = 0; kk < 8; ++kk)
        zfr[kk] = *reinterpret_cast<const bf16x8_t*>(buf2 + kk * 512 + l * 8);
      f32x4_t acc = {0.f, 0.f, 0.f, 0.f};
#pragma unroll
      for (int kk = 0; kk < 8; ++kk) acc = mfma16(zfr[kk], wzf[kk], acc);
      const u16* nyp = (const u16*)&nsv;
      bool last = (d == 9);
#pragma unroll
      for (int r = 0; r < 4; ++r) {
        int m2 = m2b + r;
        float u = acc[r] + bzr + r1[r];
        float msb = sc[16 + m2] * sigm(r0[r]);
        float yn = (1.0f - msb) * yc[r] + msb * tanh_f(u);
        float ypn = fmaf(bf2f(nyp[r]), sc[m2], yn);
        yc[r] = ypn; ylast[r] = yn;
        int slot = halfSlot(col, m2);
        stage[slot] = f2bf(yn);
        if (last) stage[2048 + slot] = f2bf(ypn);
      }
      __syncthreads();                                  // BAR_c
      cstore8(&yexch[((size_t)((s + 1) & 1) * 16 + g) * 4096 + half * 2048 + tid * 4],
              *reinterpret_cast<const uint2*>(&stage[tid * 4]));
      if (last)
        *reinterpret_cast<uint2*>(Ypack + (size_t)(tl * 16 + g) * 4096 + half * 2048 + tid * 4) =
            *reinterpret_cast<const uint2*>(&stage[2048 + tid * 4]);
      vdrain();
      __syncthreads();                                  // BAR_d
      if (tid == 0) cstore4(&flg[half * 32], (uint32_t)(s + 2));
    }
  }

  // ---- store carries ----
  if (isY) {
#pragma unroll
    for (int r = 0; r < 4; ++r) {
      int m2 = m2b + r;
      ystate[(size_t)(g * 16 + m2) * 256 + col] = yc[r];
      ypstate[(size_t)(g * 16 + m2) * 256 + col] = ylast[r];
    }
  } else {
#pragma unroll
    for (int r = 0; r < 4; ++r)
      zstate[(size_t)(g * 16 + m2b + r) * 256 + col] = zc[r];
  }
}

// out[t] = Y[t] @ W_c^T + b_c
__global__ __launch_bounds__(512) void k_out(const u16* __restrict__ Ypack, const u16* __restrict__ Wcpack,
                                             const float* __restrict__ b_c, float* __restrict__ out, int t0) {
  int tl = blockIdx.x; int mh = blockIdx.y;
  int l = threadIdx.x & 63; int wv = threadIdx.x >> 6;
  int mt = mh * 8 + wv;
  const u16* Ab = Ypack + (size_t)(tl * 16 + mt) * 4096 + (size_t)l * 8;
  bf16x8_t af[8];
#pragma unroll
  for (int kk = 0; kk < 8; ++kk) af[kk] = *reinterpret_cast<const bf16x8_t*>(Ab + kk * 512);
#pragma unroll 1
  for (int nt = 0; nt < 16; ++nt) {
    f32x4_t acc = {0.f, 0.f, 0.f, 0.f};
    const u16* bp = Wcpack + ((size_t)nt * 8 * 64 + l) * 8;
#pragma unroll
    for (int kk = 0; kk < 8; ++kk) {
      bf16x8_t bfr = *reinterpret_cast<const bf16x8_t*>(bp + kk * 512);
      acc = mfma16(af[kk], bfr, acc);
    }
    int n = (nt << 4) | (l & 15);
    float bc = b_c[n];
#pragma unroll
    for (int r = 0; r < 4; ++r) {
      int m = (mt << 4) + ((l >> 4) << 2) + r;
      out[((size_t)(t0 + tl) * 256 + m) * 256 + n] = acc[r] + bc;
    }
  }
}

// ---------------------------------------------------------------------------
extern "C" void kernel_launch(void* const* d_in, const int* in_sizes, int n_in,
                              void* d_out, int out_size, void* d_ws, size_t ws_size,
                              hipStream_t stream) {
  const float* input = (const float*)d_in[0];
  const float* dt    = (const float*)d_in[1];
  const float* W_i   = (const float*)d_in[2];
  const float* b_i   = (const float*)d_in[3];
  const float* W_h   = (const float*)d_in[4];
  const float* b_h   = (const float*)d_in[5];
  const float* W_z   = (const float*)d_in[6];
  const float* b_z   = (const float*)d_in[7];
  const float* W_dt  = (const float*)d_in[8];
  const float* b_dt  = (const float*)d_in[9];
  const float* W_c   = (const float*)d_in[10];
  const float* b_c   = (const float*)d_in[11];
  const float* W_s   = (const float*)d_in[12];
  const float* b_s   = (const float*)d_in[13];
  float* out = (float*)d_out;

  char* ws = (char*)d_ws;
  size_t off = 0;
  auto alloc = [&](size_t bytes) -> char* {
    char* p = ws + off; off = (off + bytes + 255) & ~(size_t)255; return p;
  };
  u16* Epack   = (u16*)alloc((size_t)112 * 4096 * 2);
  u16* Wipack  = (u16*)alloc((size_t)64 * 4096 * 2);
  u16* Wzpack  = (u16*)alloc((size_t)16 * 4096 * 2);
  u16* Wcpack  = (u16*)alloc((size_t)16 * 4096 * 2);
  u16* Wspack  = (u16*)alloc((size_t)32 * 16 * 512 * 2);
  u16* E2pack  = (u16*)alloc((size_t)64 * 4096 * 2);
  float* bip   = (float*)alloc(1024 * 4);
  float* biasD0= (float*)alloc(1024 * 4);
  float* biasDn= (float*)alloc(1024 * 4);
  float* Wic   = (float*)alloc((size_t)1024 * 256 * 4);
  float* ystate= (float*)alloc((size_t)256 * 256 * 4);
  float* ypstate=(float*)alloc((size_t)256 * 256 * 4);
  float* zstate= (float*)alloc((size_t)256 * 256 * 4);
  u16* yexch   = (u16*)alloc((size_t)2 * 16 * 4096 * 2);
  u16* zexch   = (u16*)alloc((size_t)2 * 16 * 4096 * 2);
  int* flags   = (int*)alloc((size_t)16 * 128 * 4);
  size_t fixed = off;
  size_t per_slot = (size_t)131072 * 2 + 65536 * 2 + 65536 * 2 + 65536 * 2;
  size_t per_t = 10 * per_slot + (size_t)10 * 196608 * 2 + 131072 + 131072;
  int Tc = 1;
  if (ws_size > fixed + per_t + per_slot) {
    size_t n = (ws_size - fixed - per_slot) / per_t;
    Tc = (n > 128) ? 128 : (int)n;
  }
  if (Tc < 1) Tc = 1;
  int maxslots = Tc * 10 + 1;
  u16* Apack   = (u16*)alloc((size_t)maxslots * 131072 * 2);
  u16* Sny     = (u16*)alloc((size_t)maxslots * 65536 * 2);
  u16* Snz     = (u16*)alloc((size_t)maxslots * 65536 * 2);
  u16* nyA     = (u16*)alloc((size_t)maxslots * 65536 * 2);
  u16* HNpack  = (u16*)alloc((size_t)(Tc * 10) * 196608 * 2);
  u16* inpPack = (u16*)alloc((size_t)Tc * 16 * 8 * 512 * 2);
  u16* Ypack   = (u16*)alloc((size_t)Tc * 16 * 8 * 512 * 2);

  hipFuncSetAttribute((const void*)k_recur, hipFuncAttributeMaxDynamicSharedMemorySize, R_LDS_BYTES);

  k_prep<<<1024, 256, 0, stream>>>(W_i, W_c, b_i, b_c, Wic, bip);
  k_bias<<<4, 256, 0, stream>>>(b_i, bip, b_h, biasD0, biasDn);
  k_packw<<<(112 * 8 * 64) / 256, 256, 0, stream>>>(Wic, 1024, W_h, Epack, 1792, 256);
  k_packw<<<(64 * 8 * 64) / 256, 256, 0, stream>>>(W_i, 1024, (const float*)nullptr, Wipack, 1024, 256);
  k_packw<<<(16 * 8 * 64) / 256, 256, 0, stream>>>(W_z, 256, (const float*)nullptr, Wzpack, 256, 256);
  k_packw<<<(16 * 8 * 64) / 256, 256, 0, stream>>>(W_c, 256, (const float*)nullptr, Wcpack, 256, 256);
  k_packw<<<(32 * 16 * 64) / 256, 256, 0, stream>>>(W_s, 512, (const float*)nullptr, Wspack, 512, 512);
  k_packe2<<<128, 256, 0, stream>>>(Wic, W_h, E2pack);

  for (int t0 = 0; t0 < 128; t0 += Tc) {
    int Tcc = (128 - t0 < Tc) ? (128 - t0) : Tc;
    int nsteps = Tcc * 10;
    int slots = nsteps + 1;
    k_gen<<<slots * 128, 1024, 0, stream>>>(Apack, t0 * 10 - 1);
    dim3 g2(slots, 4);
    k_sgemm<<<g2, 512, 0, stream>>>(Apack, Wspack, b_s, Sny, Snz, nyA);
    dim3 g3(nsteps, 6);
    k_hn<<<g3, 512, 0, stream>>>(nyA, Epack, HNpack, t0);
    int totalA = Tcc * 16 * 8 * 64;
    k_packa<<<(totalA + 255) / 256, 256, 0, stream>>>(input, t0, Tcc, inpPack);
    hipMemsetAsync(flags, 0, 16 * 128 * 4, stream);
    k_recur<<<64, 512, R_LDS_BYTES, stream>>>(dt, Epack, Wipack, Wzpack, E2pack, HNpack,
                                              biasD0, biasDn, b_z, W_dt, b_dt, inpPack, Sny, Snz,
                                              Ypack, ystate, ypstate, zstate, yexch, zexch,
                                              flags, t0, Tcc);
    dim3 ge(Tcc, 2);
    k_out<<<ge, 512, 0, stream>>>(Ypack, Wcpack, b_c, out, t0);
  }
}

// Round 12
// 7235.448 us; speedup vs baseline: 2.6125x; 1.2312x over previous
//
#include <hip/hip_runtime.h>
#include <stdint.h>

// ---------------------------------------------------------------------------
// LEM-style noisy RNN. T=128 x DIV=10 sequential steps, B=256, H=256.
// Round 12 (= round 11 + asm-type fix): self-validating 16B payloads
// {data,seq,data,seq} for the cross-WG y/z exchange (fuses flag+data: no
// vmcnt drain, no flag store, no separate data load, one less barrier/hop).
// Structure: 16 groups x 4 WGs (Y0,Y1,Z0,Z1), E2 weights LDS-resident, Wz in
// registers, in-register phase fusion, E2=Wic+Wh fold, HN=Wh@ny precompute.
// ---------------------------------------------------------------------------

typedef __attribute__((ext_vector_type(8))) short bf16x8_t;
typedef __attribute__((ext_vector_type(4))) float f32x4_t;
typedef __attribute__((ext_vector_type(4))) unsigned int u32x4_t;
typedef unsigned short u16;

#define R_LDS_BYTES 155904

__device__ __forceinline__ float bf2f(u16 b) {
  union { uint32_t u; float f; } v; v.u = ((uint32_t)b) << 16; return v.f;
}
__device__ __forceinline__ u16 f2bf(float f) {
  union { float f; uint32_t u; } v; v.f = f;
  uint32_t x = v.u;
  return (u16)((x + 0x7FFFu + ((x >> 16) & 1u)) >> 16);   // RNE
}
__device__ __forceinline__ f32x4_t mfma16(bf16x8_t a, bf16x8_t b, f32x4_t c) {
  return __builtin_amdgcn_mfma_f32_16x16x32_bf16(a, b, c, 0, 0, 0);
}
__device__ __forceinline__ float sigm(float x) { return 1.0f / (1.0f + __expf(-x)); }
__device__ __forceinline__ float tanh_f(float x) {
  float t = __expf(-2.0f * fabsf(x));
  float r = (1.0f - t) / (1.0f + t);
  return x < 0.0f ? -r : r;
}

// ---- L3-coherent (cross-XCD) transport: sc0 sc1 = bypass L1+L2 ----
__device__ __forceinline__ void cstore16(void* p, u32x4_t v) {
  asm volatile("global_store_dwordx4 %0, %1, off sc0 sc1" :: "v"(p), "v"(v) : "memory");
}
// poll two adjacent 16B payload slots until both carry seq (in words 1 and 3)
__device__ __forceinline__ void pollpair(const uint32_t* p, uint32_t seq,
                                         u32x4_t* a, u32x4_t* b) {
  while (true) {
    u32x4_t x, y;
    asm volatile("global_load_dwordx4 %0, %2, off sc0 sc1\n\t"
                 "global_load_dwordx4 %1, %3, off sc0 sc1\n\t"
                 "s_waitcnt vmcnt(0)"
                 : "=&v"(x), "=&v"(y) : "v"(p), "v"(p + 4) : "memory");
    if (x.y == seq && x.w == seq && y.y == seq && y.w == seq) { *a = x; *b = y; return; }
    __builtin_amdgcn_s_sleep(1);
  }
}
__device__ __forceinline__ u32x4_t cload16v(const void* p) {
  u32x4_t r;
  asm volatile("global_load_dwordx4 %0, %1, off sc0 sc1\n\ts_waitcnt vmcnt(0)"
               : "=&v"(r) : "v"(p) : "memory");
  return r;
}

// MFMA 16x16x32 bf16 A-frag K-position for lane l, elem e
__device__ __forceinline__ int fragK(int l, int e) {
  return ((l >> 4) << 2) + (e & 3) + ((e >> 2) << 4);
}
// A-frag local slot (within a 2048-u16 half) for row m, col h
__device__ __forceinline__ int halfSlot(int h, int m) {
  return ((h >> 5) & 3) * 512 + (((((h & 15) >> 2) << 4) | m) << 3) +
         ((h & 3) | (((h >> 4) & 1) << 2));
}

// ---- JAX threefry2x32 (20 rounds) ----
__device__ __forceinline__ void threefry(uint32_t k0, uint32_t k1, uint32_t x0, uint32_t x1,
                                         uint32_t* o0, uint32_t* o1) {
  uint32_t ks2 = k0 ^ k1 ^ 0x1BD11BDAu;
  x0 += k0; x1 += k1;
#define TFR(rot) { x0 += x1; x1 = (x1 << rot) | (x1 >> (32 - rot)); x1 ^= x0; }
  TFR(13) TFR(15) TFR(26) TFR(6)   x0 += k1;  x1 += ks2 + 1u;
  TFR(17) TFR(29) TFR(16) TFR(24)  x0 += ks2; x1 += k0 + 2u;
  TFR(13) TFR(15) TFR(26) TFR(6)   x0 += k0;  x1 += k1 + 3u;
  TFR(17) TFR(29) TFR(16) TFR(24)  x0 += k1;  x1 += ks2 + 4u;
  TFR(13) TFR(15) TFR(26) TFR(6)   x0 += ks2; x1 += k0 + 5u;
#undef TFR
  *o0 = x0; *o1 = x1;
}

// bits -> N(0,1), matches jax.random.normal f32 (XLA erfinv poly)
__device__ __forceinline__ float bits2normal(uint32_t bits) {
  union { uint32_t u; float f; } cv; cv.u = 0x3F800000u | (bits >> 9);
  float f = cv.f - 1.0f;
  float u = fmaf(f, 2.0f, -0.99999994f);
  u = fmaxf(u, -0.99999994f);
  float w = -log1pf(-u * u);
  float p;
  if (w < 5.0f) {
    w = w - 2.5f;
    p = 2.81022636e-08f;
    p = fmaf(p, w, 3.43273939e-07f);
    p = fmaf(p, w, -3.5233877e-06f);
    p = fmaf(p, w, -4.39150654e-06f);
    p = fmaf(p, w, 0.00021858087f);
    p = fmaf(p, w, -0.00125372503f);
    p = fmaf(p, w, -0.00417768164f);
    p = fmaf(p, w, 0.246640727f);
    p = fmaf(p, w, 1.50140941f);
  } else {
    w = sqrtf(w) - 3.0f;
    p = -0.000200214257f;
    p = fmaf(p, w, 0.000100950558f);
    p = fmaf(p, w, 0.00134934322f);
    p = fmaf(p, w, -0.00367342844f);
    p = fmaf(p, w, 0.00573950773f);
    p = fmaf(p, w, -0.0076224613f);
    p = fmaf(p, w, 0.00943887047f);
    p = fmaf(p, w, 1.00167406f);
    p = fmaf(p, w, 2.83297682f);
  }
  return 1.41421354f * p * u;
}

// ---------------------------------------------------------------------------
__global__ void k_prep(const float* __restrict__ W_i, const float* __restrict__ W_c,
                       const float* __restrict__ b_i, const float* __restrict__ b_c,
                       float* __restrict__ Wic, float* __restrict__ bip) {
  __shared__ float wi[256];
  __shared__ float red[256];
  int o = blockIdx.x; int tid = threadIdx.x;
  wi[tid] = W_i[o * 256 + tid];
  __syncthreads();
  float acc = 0.f;
  for (int j = 0; j < 256; ++j) acc = fmaf(wi[j], W_c[j * 256 + tid], acc);
  Wic[(size_t)o * 256 + tid] = acc;
  red[tid] = wi[tid] * b_c[tid];
  __syncthreads();
  for (int s = 128; s > 0; s >>= 1) { if (tid < s) red[tid] += red[tid + s]; __syncthreads(); }
  if (tid == 0) bip[o] = b_i[o] + red[0];
}

__global__ void k_bias(const float* __restrict__ b_i, const float* __restrict__ bip,
                       const float* __restrict__ b_h,
                       float* __restrict__ biasD0, float* __restrict__ biasDn) {
  int c = blockIdx.x * 256 + threadIdx.x;
  float bh = (c < 512) ? b_h[c] : (c >= 768 ? b_h[c - 256] : 0.f);
  biasD0[c] = b_i[c] + bh;
  biasDn[c] = bip[c] + bh;
}

__global__ void k_packw(const float* __restrict__ srcA, int rowsA, const float* __restrict__ srcB,
                        u16* __restrict__ dst, int O, int K) {
  int t = blockIdx.x * blockDim.x + threadIdx.x;
  int KK = K >> 5;
  int total = (O >> 4) * KK * 64;
  if (t >= total) return;
  int l = t & 63; int kk = (t >> 6) % KK; int to = t / (64 * KK);
  int n = (to << 4) | (l & 15);
  int kb = (kk << 5) + ((l >> 4) << 2);
  const float* src = (n < rowsA) ? (srcA + (size_t)n * K) : (srcB + (size_t)(n - rowsA) * K);
  u16 out[8];
#pragma unroll
  for (int e = 0; e < 8; ++e) out[e] = f2bf(src[kb + (e & 3) + ((e >> 2) << 4)]);
  *reinterpret_cast<uint4*>(dst + (size_t)t * 8) = *reinterpret_cast<const uint4*>(out);
}

// E2 = Wic + Wh aligned (cols 0..511 -> Wh[c], 768..1023 -> Wh[c-256]), 64 tiles
__global__ void k_packe2(const float* __restrict__ Wic, const float* __restrict__ Wh,
                         u16* __restrict__ dst) {
  int t = blockIdx.x * blockDim.x + threadIdx.x;   // 64*8*64 = 32768
  int l = t & 63; int kk = (t >> 6) & 7; int to = t >> 9;
  int n = (to << 4) | (l & 15);
  int kb = (kk << 5) + ((l >> 4) << 2);
  u16 out[8];
#pragma unroll
  for (int e = 0; e < 8; ++e) {
    int k = kb + (e & 3) + ((e >> 2) << 4);
    float v = Wic[(size_t)n * 256 + k];
    if (n < 512) v += Wh[(size_t)n * 256 + k];
    else if (n >= 768) v += Wh[(size_t)(n - 256) * 256 + k];
    out[e] = f2bf(v);
  }
  *reinterpret_cast<uint4*>(dst + (size_t)t * 8) = *reinterpret_cast<const uint4*>(out);
}

__global__ void k_packa(const float* __restrict__ inp, int t0, int Tcc, u16* __restrict__ dst) {
  int t = blockIdx.x * blockDim.x + threadIdx.x;
  int total = Tcc * 16 * 8 * 64;
  if (t >= total) return;
  int l = t & 63; int kk = (t >> 6) & 7; int mt = (t >> 9) & 15; int tl = t >> 13;
  int b = (mt << 4) | (l & 15);
  int kb = (kk << 5) + ((l >> 4) << 2);
  const float* src = inp + ((size_t)(t0 + tl) * 256 + b) * 256;
  u16 out[8];
#pragma unroll
  for (int e = 0; e < 8; ++e) out[e] = f2bf(src[kb + (e & 3) + ((e >> 2) << 4)]);
  *reinterpret_cast<uint4*>(dst + (size_t)t * 8) = *reinterpret_cast<const uint4*>(out);
}

// noise gen; slot sl = global noise step gstep0+sl (gstep0 = t0*10-1)
__global__ void k_gen(u16* __restrict__ Apack, int gstep0) {
  int sl = blockIdx.x >> 7;
  int tb = (blockIdx.x & 127) * 1024 + threadIdx.x;   // [0, 131072)
  __shared__ uint32_t kf[2];
  if (threadIdx.x == 0) {
    uint32_t o0, o1;
    threefry(0u, 1234u, 0u, (uint32_t)(gstep0 + sl), &o0, &o1);
    kf[0] = o0; kf[1] = o1;
  }
  __syncthreads();
  int e = tb & 7; int l = (tb >> 3) & 63; int kk = (tb >> 9) & 15; int mt = tb >> 13;
  int b = (mt << 4) | (l & 15);
  int c = (kk << 5) + fragK(l, e);
  uint32_t i = (uint32_t)(b * 512 + c);
  uint32_t o0, o1;
  threefry(kf[0], kf[1], 0u, i, &o0, &o1);
  Apack[(size_t)sl * 131072 + tb] = f2bf(bits2normal(o0 ^ o1));
}

// S = tanh(noise @ Ws^T + b_s) -> Sny/Snz (per (g,half), C/D-row-mapped thread
// order), and nyA (n<256 in A-frag layout, input for k_hn).
__global__ __launch_bounds__(512) void k_sgemm(const u16* __restrict__ Apack,
                                               const u16* __restrict__ Wspack,
                                               const float* __restrict__ b_s,
                                               u16* __restrict__ Sny, u16* __restrict__ Snz,
                                               u16* __restrict__ nyA) {
  int sl = blockIdx.x; int nq = blockIdx.y;
  int l = threadIdx.x & 63; int wv = threadIdx.x >> 6;
  const u16* Ab = Apack + (size_t)sl * 131072;
#pragma unroll 1
  for (int mtl = 0; mtl < 2; ++mtl) {
    int mt = 2 * wv + mtl;
    bf16x8_t af[16];
#pragma unroll
    for (int kk = 0; kk < 16; ++kk)
      af[kk] = *reinterpret_cast<const bf16x8_t*>(Ab + ((size_t)(mt * 16 + kk) * 64 + l) * 8);
#pragma unroll 1
    for (int ntl = 0; ntl < 8; ++ntl) {
      int nt = nq * 8 + ntl;
      f32x4_t acc = {0.f, 0.f, 0.f, 0.f};
#pragma unroll
      for (int kk = 0; kk < 16; ++kk) {
        bf16x8_t bfr = *reinterpret_cast<const bf16x8_t*>(Wspack + ((size_t)(nt * 16 + kk) * 64 + l) * 8);
        acc = mfma16(af[kk], bfr, acc);
      }
      int n = (nt << 4) | (l & 15);
      float bs = b_s[n];
#pragma unroll
      for (int r = 0; r < 4; ++r) {
        int m = (mt << 4) + ((l >> 4) << 2) + r;
        u16 v = f2bf(tanh_f(acc[r] + bs));
        int g = m >> 4, row = m & 15;
        if (n >= 256) {
          int h = n - 256; int hz = h >> 7;
          int tidc = ((h >> 4) & 7) * 64 + ((row >> 2) << 4) + (h & 15);
          Snz[((((size_t)sl * 16 + g) * 2 + hz) * 512 + tidc) * 4 + (row & 3)] = v;
        } else {
          int hy = n >> 7;
          int tidc = ((n >> 4) & 7) * 64 + ((row >> 2) << 4) + (n & 15);
          Sny[((((size_t)sl * 16 + g) * 2 + hy) * 512 + tidc) * 4 + (row & 3)] = v;
          int kk2 = n >> 5;
          int la = (((n & 15) >> 2) << 4) | row;
          int ea = (n & 3) | (((n >> 4) & 1) << 2);
          nyA[(((size_t)sl * 16 + g) * 8 + kk2) * 512 + la * 8 + ea] = v;
        }
      }
    }
  }
}

// HN[j] = Wh @ ny(slot j), C/D-frag layout (bf16), 48 col-tiles.
__global__ __launch_bounds__(512) void k_hn(const u16* __restrict__ nyA,
                                            const u16* __restrict__ Epack,
                                            u16* __restrict__ HNpack, int t0) {
  int j = blockIdx.x; int nq = blockIdx.y;
  int l = threadIdx.x & 63; int wv = threadIdx.x >> 6;
  int nt = nq * 8 + wv;                      // [0,48)
  if (j == 0 && t0 == 0) {
    uint2 z = {0u, 0u};
#pragma unroll 1
    for (int mt = 0; mt < 16; ++mt)
      *reinterpret_cast<uint2*>(&HNpack[(((size_t)j * 16 + mt) * 48 + nt) * 256 + l * 4]) = z;
    return;
  }
  bf16x8_t bf[8];
  const u16* bp = Epack + (size_t)(64 + nt) * 4096 + (size_t)l * 8;
#pragma unroll
  for (int kk = 0; kk < 8; ++kk)
    bf[kk] = *reinterpret_cast<const bf16x8_t*>(bp + kk * 512);
#pragma unroll 1
  for (int mt = 0; mt < 16; ++mt) {
    const u16* ap = nyA + (((size_t)j * 16 + mt) * 8) * 512 + (size_t)l * 8;
    f32x4_t acc = {0.f, 0.f, 0.f, 0.f};
#pragma unroll
    for (int kk = 0; kk < 8; ++kk)
      acc = mfma16(*reinterpret_cast<const bf16x8_t*>(ap + kk * 512), bf[kk], acc);
    union { u16 h[4]; uint2 v; } o;
#pragma unroll
    for (int r = 0; r < 4; ++r) o.h[r] = f2bf(acc[r]);
    *reinterpret_cast<uint2*>(&HNpack[(((size_t)j * 16 + mt) * 48 + nt) * 256 + l * 4]) = o.v;
  }
}

// ---------------------------------------------------------------------------
// Recurrence, 64 WGs x 512. wgid = role*16 + g. role 0/1 = Y(hy), 2/3 = Z(hz).
// Exchange: self-validating 16B payload slots {data0, seq, data1, seq};
// slot j carries frag bytes [8j, 8j+8); producer slot = half*512 + tid;
// consumer tid polls slots 2tid, 2tid+1. seq = t0*10 + s + 1 (y: +2 at pub).
__global__ __launch_bounds__(512, 2) void k_recur(
    const float* __restrict__ dt,
    const u16* __restrict__ Epack, const u16* __restrict__ Wipack, const u16* __restrict__ Wzpack,
    const u16* __restrict__ E2pack, const u16* __restrict__ HNpack,
    const float* __restrict__ biasD0, const float* __restrict__ biasDn,
    const float* __restrict__ b_z, const float* __restrict__ W_dt, const float* __restrict__ b_dt,
    const u16* __restrict__ inpPack, const u16* __restrict__ Sny, const u16* __restrict__ Snz,
    u16* __restrict__ Ypack, float* __restrict__ ystate, float* __restrict__ ypstate,
    float* __restrict__ zstate,
    uint32_t* __restrict__ yexch, uint32_t* __restrict__ zexch,
    int t0, int Tcc)
{
  extern __shared__ char lds_raw[];
  u16* wlds  = (u16*)lds_raw;                 // [16][4096] E2 tiles (128KB)
  u16* ypb   = wlds + 65536;                  // 4096: y_pre frags
  u16* buf2  = ypb + 4096;                    // 4096: Z: x frags @d0; Y: z frags
  u16* stage = buf2 + 4096;                   // 4096: Z: z-stage; Y: x@d0 / y-stage + ypn@d9
  float* sc  = (float*)(stage + 4096);        // 48
  float* scP = sc + 48;                       // 16

  const int wgid = blockIdx.x;
  const int g = wgid & 15;
  const int role = wgid >> 4;
  const bool isY = role < 2;
  const int half = role & 1;
  const int tid = threadIdx.x;
  const int l = tid & 63;
  const int wv = tid >> 6;
  const int nsteps = Tcc * 10;
  const int m2b = 4 * (l >> 4);
  const int col = half * 128 + wv * 16 + (l & 15);
  const uint32_t gb = (uint32_t)(t0 * 10);

  // tile ids
  int wiT0, whT0, hnT0, wiT1, whT1 = -1, hnT1 = -1;
  if (isY) {
    wiT0 = half * 8 + wv;       whT0 = 64 + wiT0;  hnT0 = wiT0;
    wiT1 = 32 + half * 8 + wv;
  } else {
    wiT0 = 16 + half * 8 + wv;  whT0 = 64 + wiT0;  hnT0 = wiT0;
    wiT1 = 48 + half * 8 + wv;  whT1 = 96 + half * 8 + wv;  hnT1 = 32 + half * 8 + wv;
  }
  float b0d0 = biasD0[wiT0 * 16 + (l & 15)], b0dn = biasDn[wiT0 * 16 + (l & 15)];
  float b1d0 = biasD0[wiT1 * 16 + (l & 15)], b1dn = biasDn[wiT1 * 16 + (l & 15)];

  // ---- preload E2 weight tiles into LDS ----
  for (int i = tid; i < 8192; i += 512) {
    int t = i >> 9; int o = (i & 511) << 3;
    int gt;
    if (isY) gt = (t < 8) ? (half * 8 + t) : (32 + half * 8 + (t - 8));
    else     gt = (t < 8) ? (16 + half * 8 + t) : (48 + half * 8 + (t - 8));
    *reinterpret_cast<uint4*>(wlds + t * 4096 + o) =
        *reinterpret_cast<const uint4*>(E2pack + (size_t)gt * 4096 + o);
  }

  float zc[4], yc[4], ylast[4];
  bf16x8_t wzf[8];
  float bzr = 0.f;

  if (isY) {
    bzr = b_z[col];
#pragma unroll
    for (int kk = 0; kk < 8; ++kk)
      wzf[kk] = *reinterpret_cast<const bf16x8_t*>(
          Wzpack + (size_t)(half * 8 + wv) * 4096 + (size_t)kk * 512 + (size_t)l * 8);
#pragma unroll
    for (int r = 0; r < 4; ++r) {
      int m2 = m2b + r;
      yc[r] = (t0 == 0) ? 0.f : ystate[(size_t)(g * 16 + m2) * 256 + col];
      ylast[r] = 0.f;
      float v = (t0 == 0) ? 0.f : ypstate[(size_t)(g * 16 + m2) * 256 + col];
      stage[halfSlot(col, m2)] = f2bf(v);
    }
    __syncthreads();
    {
      uint2 dv = *reinterpret_cast<const uint2*>(&stage[tid * 4]);
      uint32_t sq = gb + 1u;
      u32x4_t pay = {dv.x, sq, dv.y, sq};
      cstore16(yexch + ((size_t)g * 1024 + half * 512 + tid) * 4, pay);
    }
  } else {
#pragma unroll
    for (int r = 0; r < 4; ++r)
      zc[r] = (t0 == 0) ? 0.f : zstate[(size_t)(g * 16 + m2b + r) * 256 + col];
  }

  float wdt0 = W_dt[0], wdt1 = W_dt[1], bdt0 = b_dt[0], bdt1 = b_dt[1];

  for (int s = 0; s < nsteps; ++s) {
    int d = s % 10, tl = s / 10;
    // prefetch (normal loads; latency hides under the poll)
    const u16* SnX = isY ? Sny : Snz;
    uint2 nsv = *reinterpret_cast<const uint2*>(
        SnX + ((((size_t)(s + 1) * 16 + g) * 2 + half) * 512 + tid) * 4);
    size_t HNs = ((size_t)s * 16 + g) * 48;
    uint2 hv0 = *reinterpret_cast<const uint2*>(HNpack + (HNs + hnT0) * 256 + l * 4);
    uint2 hv1 = {0u, 0u};
    if (!isY) hv1 = *reinterpret_cast<const uint2*>(HNpack + (HNs + hnT1) * 256 + l * 4);
    if (d == 0 && tid < 16) {
      float dl = dt[(size_t)(t0 + tl) * 256 + g * 16 + tid] * 0.1f;
      sc[tid] = dl;
      sc[16 + tid] = sigm(fmaf(dl, wdt0, bdt0));
      sc[32 + tid] = sigm(fmaf(dl, wdt1, bdt1));
      int tp = t0 + tl - 1; if (tp < 0) tp = 0;
      scP[tid] = dt[(size_t)tp * 256 + g * 16 + tid] * 0.1f;
    }
    // ---- wait y(s): poll self-validating slots ----
    {
      u32x4_t p0, p1;
      pollpair(yexch + (((size_t)(s & 1) * 16 + g) * 1024 + 2 * tid) * 4, gb + (uint32_t)s + 1u,
               &p0, &p1);
      uint2 w0 = {p0.x, p0.z}, w1 = {p1.x, p1.z};
      *reinterpret_cast<uint2*>(ypb + tid * 8) = w0;
      *reinterpret_cast<uint2*>(ypb + tid * 8 + 4) = w1;
      if (d == 0) {
        u16* xb = isY ? stage : buf2;
        *reinterpret_cast<uint4*>(xb + tid * 8) =
            *reinterpret_cast<const uint4*>(inpPack + (size_t)(tl * 16 + g) * 4096 + tid * 8);
      }
    }
    __syncthreads();                                    // BAR_a

    // ---- Phase A: both panels of this wave's column tile, in-register ----
    f32x4_t r0, r1;
    {
      bf16x8_t ay[8];
#pragma unroll
      for (int kk = 0; kk < 8; ++kk)
        ay[kk] = *reinterpret_cast<const bf16x8_t*>(ypb + kk * 512 + l * 8);
      float scv[4];
#pragma unroll
      for (int r = 0; r < 4; ++r) scv[r] = (d == 0 ? scP[m2b + r] : sc[m2b + r]);
      f32x4_t a0 = {0.f, 0.f, 0.f, 0.f}, a1 = {0.f, 0.f, 0.f, 0.f};
      if (d == 0) {
        bf16x8_t ax[8];
        const u16* xb = isY ? stage : buf2;
#pragma unroll
        for (int kk = 0; kk < 8; ++kk)
          ax[kk] = *reinterpret_cast<const bf16x8_t*>(xb + kk * 512 + l * 8);
        const u16* bp0 = Wipack + (size_t)wiT0 * 4096 + (size_t)l * 8;
        const u16* hp0 = Epack + (size_t)whT0 * 4096 + (size_t)l * 8;
#pragma unroll
        for (int kk = 0; kk < 8; ++kk)
          a0 = mfma16(ax[kk], *reinterpret_cast<const bf16x8_t*>(bp0 + kk * 512), a0);
#pragma unroll
        for (int kk = 0; kk < 8; ++kk)
          a0 = mfma16(ay[kk], *reinterpret_cast<const bf16x8_t*>(hp0 + kk * 512), a0);
        const u16* bp1 = Wipack + (size_t)wiT1 * 4096 + (size_t)l * 8;
#pragma unroll
        for (int kk = 0; kk < 8; ++kk)
          a1 = mfma16(ax[kk], *reinterpret_cast<const bf16x8_t*>(bp1 + kk * 512), a1);
        if (!isY) {
          const u16* hp1 = Epack + (size_t)whT1 * 4096 + (size_t)l * 8;
#pragma unroll
          for (int kk = 0; kk < 8; ++kk)
            a1 = mfma16(ay[kk], *reinterpret_cast<const bf16x8_t*>(hp1 + kk * 512), a1);
        }
      } else {
        const u16* w0 = wlds + wv * 4096 + l * 8;
        const u16* w1 = wlds + (8 + wv) * 4096 + l * 8;
#pragma unroll
        for (int kk = 0; kk < 8; ++kk)
          a0 = mfma16(ay[kk], *reinterpret_cast<const bf16x8_t*>(w0 + kk * 512), a0);
#pragma unroll
        for (int kk = 0; kk < 8; ++kk)
          a1 = mfma16(ay[kk], *reinterpret_cast<const bf16x8_t*>(w1 + kk * 512), a1);
      }
      const u16* h0 = (const u16*)&hv0;
#pragma unroll
      for (int r = 0; r < 4; ++r)
        r0[r] = a0[r] + (d == 0 ? b0d0 : b0dn) + scv[r] * bf2f(h0[r]);
      if (!isY) {
        const u16* h1 = (const u16*)&hv1;
#pragma unroll
        for (int r = 0; r < 4; ++r)
          r1[r] = a1[r] + (d == 0 ? b1d0 : b1dn) + scv[r] * bf2f(h1[r]);
      } else {
#pragma unroll
        for (int r = 0; r < 4; ++r)
          r1[r] = a1[r] + (d == 0 ? b1d0 : b1dn);
      }
    }

    if (!isY) {
      // ---- Phase B: z update in-register; stage half; payload publish ----
      const u16* nzp = (const u16*)&nsv;
#pragma unroll
      for (int r = 0; r < 4; ++r) {
        int m2 = m2b + r;
        float ms = sc[32 + m2] * sigm(r0[r]);
        float zn = (1.0f - ms) * zc[r] + ms * tanh_f(r1[r]);
        stage[halfSlot(col, m2)] = f2bf(zn);
        zc[r] = fmaf(bf2f(nzp[r]), sc[m2], zn);
      }
      __syncthreads();                                  // BAR_b
      {
        uint2 dv = *reinterpret_cast<const uint2*>(&stage[tid * 4]);
        uint32_t sq = gb + (uint32_t)s + 1u;
        u32x4_t pay = {dv.x, sq, dv.y, sq};
        cstore16(zexch + (((size_t)(s & 1) * 16 + g) * 1024 + half * 512 + tid) * 4, pay);
      }
    } else {
      // ---- wait z(s): poll self-validating slots ----
      {
        u32x4_t p0, p1;
        pollpair(zexch + (((size_t)(s & 1) * 16 + g) * 1024 + 2 * tid) * 4, gb + (uint32_t)s + 1u,
                 &p0, &p1);
        uint2 w0 = {p0.x, p0.z}, w1 = {p1.x, p1.z};
        *reinterpret_cast<uint2*>(buf2 + tid * 8) = w0;
        *reinterpret_cast<uint2*>(buf2 + tid * 8 + 4) = w1;
      }
      __syncthreads();                                  // BAR_b
      // ---- Phase C: Wz MFMA (reg weights) + y update in-register ----
      bf16x8_t zfr[8];
#pragma unroll
      for (int kk = 0; kk < 8; ++kk)
        zfr[kk] = *reinterpret_cast<const bf16x8_t*>(buf2 + kk * 512 + l * 8);
      f32x4_t acc = {0.f, 0.f, 0.f, 0.f};
#pragma unroll
      for (int kk = 0; kk < 8; ++kk) acc = mfma16(zfr[kk], wzf[kk], acc);
      const u16* nyp = (const u16*)&nsv;
      bool last = (d == 9);
#pragma unroll
      for (int r = 0; r < 4; ++r) {
        int m2 = m2b + r;
        float u = acc[r] + bzr + r1[r];
        float msb = sc[16 + m2] * sigm(r0[r]);
        float yn = (1.0f - msb) * yc[r] + msb * tanh_f(u);
        float ypn = fmaf(bf2f(nyp[r]), sc[m2], yn);
        yc[r] = ypn; ylast[r] = yn;
        int slot = halfSlot(col, m2);
        stage[slot] = f2bf(yn);
        if (last) stage[2048 + slot] = f2bf(ypn);
      }
      __syncthreads();                                  // BAR_c
      {
        uint2 dv = *reinterpret_cast<const uint2*>(&stage[tid * 4]);
        uint32_t sq = gb + (uint32_t)s + 2u;
        u32x4_t pay = {dv.x, sq, dv.y, sq};
        cstore16(yexch + (((size_t)((s + 1) & 1) * 16 + g) * 1024 + half * 512 + tid) * 4, pay);
        if (last)
          *reinterpret_cast<uint2*>(Ypack + (size_t)(tl * 16 + g) * 4096 + half * 2048 + tid * 4) =
              *reinterpret_cast<const uint2*>(&stage[2048 + tid * 4]);
      }
    }
  }

  // ---- store carries ----
  if (isY) {
#pragma unroll
    for (int r = 0; r < 4; ++r) {
      int m2 = m2b + r;
      ystate[(size_t)(g * 16 + m2) * 256 + col] = yc[r];
      ypstate[(size_t)(g * 16 + m2) * 256 + col] = ylast[r];
    }
  } else {
#pragma unroll
    for (int r = 0; r < 4; ++r)
      zstate[(size_t)(g * 16 + m2b + r) * 256 + col] = zc[r];
  }
}

// out[t] = Y[t] @ W_c^T + b_c
__global__ __launch_bounds__(512) void k_out(const u16* __restrict__ Ypack, const u16* __restrict__ Wcpack,
                                             const float* __restrict__ b_c, float* __restrict__ out, int t0) {
  int tl = blockIdx.x; int mh = blockIdx.y;
  int l = threadIdx.x & 63; int wv = threadIdx.x >> 6;
  int mt = mh * 8 + wv;
  const u16* Ab = Ypack + (size_t)(tl * 16 + mt) * 4096 + (size_t)l * 8;
  bf16x8_t af[8];
#pragma unroll
  for (int kk = 0; kk < 8; ++kk) af[kk] = *reinterpret_cast<const bf16x8_t*>(Ab + kk * 512);
#pragma unroll 1
  for (int nt = 0; nt < 16; ++nt) {
    f32x4_t acc = {0.f, 0.f, 0.f, 0.f};
    const u16* bp = Wcpack + ((size_t)nt * 8 * 64 + l) * 8;
#pragma unroll
    for (int kk = 0; kk < 8; ++kk) {
      bf16x8_t bfr = *reinterpret_cast<const bf16x8_t*>(bp + kk * 512);
      acc = mfma16(af[kk], bfr, acc);
    }
    int n = (nt << 4) | (l & 15);
    float bc = b_c[n];
#pragma unroll
    for (int r = 0; r < 4; ++r) {
      int m = (mt << 4) + ((l >> 4) << 2) + r;
      out[((size_t)(t0 + tl) * 256 + m) * 256 + n] = acc[r] + bc;
    }
  }
}

// ---------------------------------------------------------------------------
extern "C" void kernel_launch(void* const* d_in, const int* in_sizes, int n_in,
                              void* d_out, int out_size, void* d_ws, size_t ws_size,
                              hipStream_t stream) {
  const float* input = (const float*)d_in[0];
  const float* dt    = (const float*)d_in[1];
  const float* W_i   = (const float*)d_in[2];
  const float* b_i   = (const float*)d_in[3];
  const float* W_h   = (const float*)d_in[4];
  const float* b_h   = (const float*)d_in[5];
  const float* W_z   = (const float*)d_in[6];
  const float* b_z   = (const float*)d_in[7];
  const float* W_dt  = (const float*)d_in[8];
  const float* b_dt  = (const float*)d_in[9];
  const float* W_c   = (const float*)d_in[10];
  const float* b_c   = (const float*)d_in[11];
  const float* W_s   = (const float*)d_in[12];
  const float* b_s   = (const float*)d_in[13];
  float* out = (float*)d_out;

  char* ws = (char*)d_ws;
  size_t off = 0;
  auto alloc = [&](size_t bytes) -> char* {
    char* p = ws + off; off = (off + bytes + 255) & ~(size_t)255; return p;
  };
  u16* Epack   = (u16*)alloc((size_t)112 * 4096 * 2);
  u16* Wipack  = (u16*)alloc((size_t)64 * 4096 * 2);
  u16* Wzpack  = (u16*)alloc((size_t)16 * 4096 * 2);
  u16* Wcpack  = (u16*)alloc((size_t)16 * 4096 * 2);
  u16* Wspack  = (u16*)alloc((size_t)32 * 16 * 512 * 2);
  u16* E2pack  = (u16*)alloc((size_t)64 * 4096 * 2);
  float* bip   = (float*)alloc(1024 * 4);
  float* biasD0= (float*)alloc(1024 * 4);
  float* biasDn= (float*)alloc(1024 * 4);
  float* Wic   = (float*)alloc((size_t)1024 * 256 * 4);
  float* ystate= (float*)alloc((size_t)256 * 256 * 4);
  float* ypstate=(float*)alloc((size_t)256 * 256 * 4);
  float* zstate= (float*)alloc((size_t)256 * 256 * 4);
  uint32_t* yexch = (uint32_t*)alloc((size_t)2 * 16 * 1024 * 16);   // payload slots
  uint32_t* zexch = (uint32_t*)alloc((size_t)2 * 16 * 1024 * 16);
  size_t fixed = off;
  size_t per_slot = (size_t)131072 * 2 + 65536 * 2 + 65536 * 2 + 65536 * 2;
  size_t per_t = 10 * per_slot + (size_t)10 * 196608 * 2 + 131072 + 131072;
  int Tc = 1;
  if (ws_size > fixed + per_t + per_slot) {
    size_t n = (ws_size - fixed - per_slot) / per_t;
    Tc = (n > 128) ? 128 : (int)n;
  }
  if (Tc < 1) Tc = 1;
  int maxslots = Tc * 10 + 1;
  u16* Apack   = (u16*)alloc((size_t)maxslots * 131072 * 2);
  u16* Sny     = (u16*)alloc((size_t)maxslots * 65536 * 2);
  u16* Snz     = (u16*)alloc((size_t)maxslots * 65536 * 2);
  u16* nyA     = (u16*)alloc((size_t)maxslots * 65536 * 2);
  u16* HNpack  = (u16*)alloc((size_t)(Tc * 10) * 196608 * 2);
  u16* inpPack = (u16*)alloc((size_t)Tc * 16 * 8 * 512 * 2);
  u16* Ypack   = (u16*)alloc((size_t)Tc * 16 * 8 * 512 * 2);

  (void)hipFuncSetAttribute((const void*)k_recur, hipFuncAttributeMaxDynamicSharedMemorySize,
                            R_LDS_BYTES);

  k_prep<<<1024, 256, 0, stream>>>(W_i, W_c, b_i, b_c, Wic, bip);
  k_bias<<<4, 256, 0, stream>>>(b_i, bip, b_h, biasD0, biasDn);
  k_packw<<<(112 * 8 * 64) / 256, 256, 0, stream>>>(Wic, 1024, W_h, Epack, 1792, 256);
  k_packw<<<(64 * 8 * 64) / 256, 256, 0, stream>>>(W_i, 1024, (const float*)nullptr, Wipack, 1024, 256);
  k_packw<<<(16 * 8 * 64) / 256, 256, 0, stream>>>(W_z, 256, (const float*)nullptr, Wzpack, 256, 256);
  k_packw<<<(16 * 8 * 64) / 256, 256, 0, stream>>>(W_c, 256, (const float*)nullptr, Wcpack, 256, 256);
  k_packw<<<(32 * 16 * 64) / 256, 256, 0, stream>>>(W_s, 512, (const float*)nullptr, Wspack, 512, 512);
  k_packe2<<<128, 256, 0, stream>>>(Wic, W_h, E2pack);

  for (int t0 = 0; t0 < 128; t0 += Tc) {
    int Tcc = (128 - t0 < Tc) ? (128 - t0) : Tc;
    int nsteps = Tcc * 10;
    int slots = nsteps + 1;
    k_gen<<<slots * 128, 1024, 0, stream>>>(Apack, t0 * 10 - 1);
    dim3 g2(slots, 4);
    k_sgemm<<<g2, 512, 0, stream>>>(Apack, Wspack, b_s, Sny, Snz, nyA);
    dim3 g3(nsteps, 6);
    k_hn<<<g3, 512, 0, stream>>>(nyA, Epack, HNpack, t0);
    int totalA = Tcc * 16 * 8 * 64;
    k_packa<<<(totalA + 255) / 256, 256, 0, stream>>>(input, t0, Tcc, inpPack);
    k_recur<<<64, 512, R_LDS_BYTES, stream>>>(dt, Epack, Wipack, Wzpack, E2pack, HNpack,
                                              biasD0, biasDn, b_z, W_dt, b_dt, inpPack, Sny, Snz,
                                              Ypack, ystate, ypstate, zstate, yexch, zexch,
                                              t0, Tcc);
    dim3 ge(Tcc, 2);
    k_out<<<ge, 512, 0, stream>>>(Ypack, Wcpack, b_c, out, t0);
  }
}

// Round 13
// 7105.899 us; speedup vs baseline: 2.6601x; 1.0182x over previous
//
#include <hip/hip_runtime.h>
#include <stdint.h>

// ---------------------------------------------------------------------------
// LEM-style noisy RNN. T=128 x DIV=10 sequential steps, B=256, H=256.
// Round 13: latency-trimmed exchange.
//  - Dual-path publish: payload stored to L3 (sc0 sc1, correct cross-XCD) AND
//    to same-XCD L2 (sc0, fast path; roles of a group co-locate per round-robin
//    wgid%8). Consumers poll L2 first, L3 fallback each iteration.
//  - Publishes go DIRECTLY from registers in C/D order; CONSUMER scatters into
//    A-frag LDS (producer staging + one barrier per hop deleted).
//  - XI = Wi@x precomputed (k_xi) -> d==0 streams only Wh tiles.
//  - Structure: 16 groups x 4 WGs (Y0,Y1,Z0,Z1), E2 LDS-resident, Wz in regs,
//    in-register phase fusion, E2=Wic+Wh fold, HN=Wh@ny precompute.
// ---------------------------------------------------------------------------

typedef __attribute__((ext_vector_type(8))) short bf16x8_t;
typedef __attribute__((ext_vector_type(4))) float f32x4_t;
typedef __attribute__((ext_vector_type(4))) unsigned int u32x4_t;
typedef unsigned short u16;

#define R_LDS_BYTES 147712

__device__ __forceinline__ float bf2f(u16 b) {
  union { uint32_t u; float f; } v; v.u = ((uint32_t)b) << 16; return v.f;
}
__device__ __forceinline__ u16 f2bf(float f) {
  union { float f; uint32_t u; } v; v.f = f;
  uint32_t x = v.u;
  return (u16)((x + 0x7FFFu + ((x >> 16) & 1u)) >> 16);   // RNE
}
__device__ __forceinline__ f32x4_t mfma16(bf16x8_t a, bf16x8_t b, f32x4_t c) {
  return __builtin_amdgcn_mfma_f32_16x16x32_bf16(a, b, c, 0, 0, 0);
}
__device__ __forceinline__ float sigm(float x) { return 1.0f / (1.0f + __expf(-x)); }
__device__ __forceinline__ float tanh_f(float x) {
  float t = __expf(-2.0f * fabsf(x));
  float r = (1.0f - t) / (1.0f + t);
  return x < 0.0f ? -r : r;
}

// A-frag slot for (k in [0,256), row m in [0,16))
__device__ __forceinline__ int fslot(int k, int m) {
  return ((k >> 5) * 512) + (((((k & 15) >> 2) << 4) | m) << 3) +
         ((k & 3) | (((k >> 4) & 1) << 2));
}
// MFMA 16x16x32 bf16 A-frag K-position for lane l, elem e
__device__ __forceinline__ int fragK(int l, int e) {
  return ((l >> 4) << 2) + (e & 3) + ((e >> 2) << 4);
}

// ---- dual-path transport ----
__device__ __forceinline__ void publish(uint32_t* p3, uint32_t* p2,
                                        uint32_t w0, uint32_t w1, uint32_t seq) {
  u32x4_t pay; pay.x = w0; pay.y = seq; pay.z = w1; pay.w = seq;
  asm volatile("global_store_dwordx4 %0, %2, off sc0 sc1\n\t"
               "global_store_dwordx4 %1, %2, off sc0"
               :: "v"(p3), "v"(p2), "v"(pay) : "memory");
}
__device__ __forceinline__ void pollpair_dual(const uint32_t* p2, const uint32_t* p3,
                                              uint32_t seq, u32x4_t* a, u32x4_t* b) {
  while (true) {
    u32x4_t x, y;
    asm volatile("global_load_dwordx4 %0, %2, off sc0\n\t"
                 "global_load_dwordx4 %1, %3, off sc0\n\t"
                 "s_waitcnt vmcnt(0)"
                 : "=&v"(x), "=&v"(y) : "v"(p2), "v"(p2 + 4) : "memory");
    if (x.y == seq && x.w == seq && y.y == seq && y.w == seq) { *a = x; *b = y; return; }
    asm volatile("global_load_dwordx4 %0, %2, off sc0 sc1\n\t"
                 "global_load_dwordx4 %1, %3, off sc0 sc1\n\t"
                 "s_waitcnt vmcnt(0)"
                 : "=&v"(x), "=&v"(y) : "v"(p3), "v"(p3 + 4) : "memory");
    if (x.y == seq && x.w == seq && y.y == seq && y.w == seq) { *a = x; *b = y; return; }
    __builtin_amdgcn_s_sleep(1);
  }
}
__device__ __forceinline__ void poll1_dual(const uint32_t* p2, const uint32_t* p3,
                                           uint32_t seq, u32x4_t* a) {
  while (true) {
    u32x4_t x;
    asm volatile("global_load_dwordx4 %0, %1, off sc0\n\ts_waitcnt vmcnt(0)"
                 : "=&v"(x) : "v"(p2) : "memory");
    if (x.y == seq && x.w == seq) { *a = x; return; }
    asm volatile("global_load_dwordx4 %0, %1, off sc0 sc1\n\ts_waitcnt vmcnt(0)"
                 : "=&v"(x) : "v"(p3) : "memory");
    if (x.y == seq && x.w == seq) { *a = x; return; }
    __builtin_amdgcn_s_sleep(1);
  }
}
// scatter one C/D-order payload slot j into A-frag LDS
__device__ __forceinline__ void scatter2(u16* dst, int j, u32x4_t p) {
  int wvp = (j >> 6) & 7, lp = j & 63, hf = j >> 9;
  int colp = hf * 128 + wvp * 16 + (lp & 15);
  int mb = 4 * (lp >> 4);
  int base = fslot(colp, mb);
  dst[base]      = (u16)(p.x & 0xffffu);
  dst[base + 8]  = (u16)(p.x >> 16);
  dst[base + 16] = (u16)(p.z & 0xffffu);
  dst[base + 24] = (u16)(p.z >> 16);
}

// ---- JAX threefry2x32 (20 rounds) ----
__device__ __forceinline__ void threefry(uint32_t k0, uint32_t k1, uint32_t x0, uint32_t x1,
                                         uint32_t* o0, uint32_t* o1) {
  uint32_t ks2 = k0 ^ k1 ^ 0x1BD11BDAu;
  x0 += k0; x1 += k1;
#define TFR(rot) { x0 += x1; x1 = (x1 << rot) | (x1 >> (32 - rot)); x1 ^= x0; }
  TFR(13) TFR(15) TFR(26) TFR(6)   x0 += k1;  x1 += ks2 + 1u;
  TFR(17) TFR(29) TFR(16) TFR(24)  x0 += ks2; x1 += k0 + 2u;
  TFR(13) TFR(15) TFR(26) TFR(6)   x0 += k0;  x1 += k1 + 3u;
  TFR(17) TFR(29) TFR(16) TFR(24)  x0 += k1;  x1 += ks2 + 4u;
  TFR(13) TFR(15) TFR(26) TFR(6)   x0 += ks2; x1 += k0 + 5u;
#undef TFR
  *o0 = x0; *o1 = x1;
}

// bits -> N(0,1), matches jax.random.normal f32 (XLA erfinv poly)
__device__ __forceinline__ float bits2normal(uint32_t bits) {
  union { uint32_t u; float f; } cv; cv.u = 0x3F800000u | (bits >> 9);
  float f = cv.f - 1.0f;
  float u = fmaf(f, 2.0f, -0.99999994f);
  u = fmaxf(u, -0.99999994f);
  float w = -log1pf(-u * u);
  float p;
  if (w < 5.0f) {
    w = w - 2.5f;
    p = 2.81022636e-08f;
    p = fmaf(p, w, 3.43273939e-07f);
    p = fmaf(p, w, -3.5233877e-06f);
    p = fmaf(p, w, -4.39150654e-06f);
    p = fmaf(p, w, 0.00021858087f);
    p = fmaf(p, w, -0.00125372503f);
    p = fmaf(p, w, -0.00417768164f);
    p = fmaf(p, w, 0.246640727f);
    p = fmaf(p, w, 1.50140941f);
  } else {
    w = sqrtf(w) - 3.0f;
    p = -0.000200214257f;
    p = fmaf(p, w, 0.000100950558f);
    p = fmaf(p, w, 0.00134934322f);
    p = fmaf(p, w, -0.00367342844f);
    p = fmaf(p, w, 0.00573950773f);
    p = fmaf(p, w, -0.0076224613f);
    p = fmaf(p, w, 0.00943887047f);
    p = fmaf(p, w, 1.00167406f);
    p = fmaf(p, w, 2.83297682f);
  }
  return 1.41421354f * p * u;
}

// ---------------------------------------------------------------------------
__global__ void k_prep(const float* __restrict__ W_i, const float* __restrict__ W_c,
                       const float* __restrict__ b_i, const float* __restrict__ b_c,
                       float* __restrict__ Wic, float* __restrict__ bip) {
  __shared__ float wi[256];
  __shared__ float red[256];
  int o = blockIdx.x; int tid = threadIdx.x;
  wi[tid] = W_i[o * 256 + tid];
  __syncthreads();
  float acc = 0.f;
  for (int j = 0; j < 256; ++j) acc = fmaf(wi[j], W_c[j * 256 + tid], acc);
  Wic[(size_t)o * 256 + tid] = acc;
  red[tid] = wi[tid] * b_c[tid];
  __syncthreads();
  for (int s = 128; s > 0; s >>= 1) { if (tid < s) red[tid] += red[tid + s]; __syncthreads(); }
  if (tid == 0) bip[o] = b_i[o] + red[0];
}

__global__ void k_bias(const float* __restrict__ b_i, const float* __restrict__ bip,
                       const float* __restrict__ b_h,
                       float* __restrict__ biasD0, float* __restrict__ biasDn) {
  int c = blockIdx.x * 256 + threadIdx.x;
  float bh = (c < 512) ? b_h[c] : (c >= 768 ? b_h[c - 256] : 0.f);
  biasD0[c] = b_i[c] + bh;
  biasDn[c] = bip[c] + bh;
}

__global__ void k_packw(const float* __restrict__ srcA, int rowsA, const float* __restrict__ srcB,
                        u16* __restrict__ dst, int O, int K) {
  int t = blockIdx.x * blockDim.x + threadIdx.x;
  int KK = K >> 5;
  int total = (O >> 4) * KK * 64;
  if (t >= total) return;
  int l = t & 63; int kk = (t >> 6) % KK; int to = t / (64 * KK);
  int n = (to << 4) | (l & 15);
  int kb = (kk << 5) + ((l >> 4) << 2);
  const float* src = (n < rowsA) ? (srcA + (size_t)n * K) : (srcB + (size_t)(n - rowsA) * K);
  u16 out[8];
#pragma unroll
  for (int e = 0; e < 8; ++e) out[e] = f2bf(src[kb + (e & 3) + ((e >> 2) << 4)]);
  *reinterpret_cast<uint4*>(dst + (size_t)t * 8) = *reinterpret_cast<const uint4*>(out);
}

// E2 = Wic + Wh aligned (cols 0..511 -> Wh[c], 768..1023 -> Wh[c-256]), 64 tiles
__global__ void k_packe2(const float* __restrict__ Wic, const float* __restrict__ Wh,
                         u16* __restrict__ dst) {
  int t = blockIdx.x * blockDim.x + threadIdx.x;   // 64*8*64 = 32768
  int l = t & 63; int kk = (t >> 6) & 7; int to = t >> 9;
  int n = (to << 4) | (l & 15);
  int kb = (kk << 5) + ((l >> 4) << 2);
  u16 out[8];
#pragma unroll
  for (int e = 0; e < 8; ++e) {
    int k = kb + (e & 3) + ((e >> 2) << 4);
    float v = Wic[(size_t)n * 256 + k];
    if (n < 512) v += Wh[(size_t)n * 256 + k];
    else if (n >= 768) v += Wh[(size_t)(n - 256) * 256 + k];
    out[e] = f2bf(v);
  }
  *reinterpret_cast<uint4*>(dst + (size_t)t * 8) = *reinterpret_cast<const uint4*>(out);
}

__global__ void k_packa(const float* __restrict__ inp, int t0, int Tcc, u16* __restrict__ dst) {
  int t = blockIdx.x * blockDim.x + threadIdx.x;
  int total = Tcc * 16 * 8 * 64;
  if (t >= total) return;
  int l = t & 63; int kk = (t >> 6) & 7; int mt = (t >> 9) & 15; int tl = t >> 13;
  int b = (mt << 4) | (l & 15);
  int kb = (kk << 5) + ((l >> 4) << 2);
  const float* src = inp + ((size_t)(t0 + tl) * 256 + b) * 256;
  u16 out[8];
#pragma unroll
  for (int e = 0; e < 8; ++e) out[e] = f2bf(src[kb + (e & 3) + ((e >> 2) << 4)]);
  *reinterpret_cast<uint4*>(dst + (size_t)t * 8) = *reinterpret_cast<const uint4*>(out);
}

// noise gen; slot sl = global noise step gstep0+sl (gstep0 = t0*10-1)
__global__ void k_gen(u16* __restrict__ Apack, int gstep0) {
  int sl = blockIdx.x >> 7;
  int tb = (blockIdx.x & 127) * 1024 + threadIdx.x;   // [0, 131072)
  __shared__ uint32_t kf[2];
  if (threadIdx.x == 0) {
    uint32_t o0, o1;
    threefry(0u, 1234u, 0u, (uint32_t)(gstep0 + sl), &o0, &o1);
    kf[0] = o0; kf[1] = o1;
  }
  __syncthreads();
  int e = tb & 7; int l = (tb >> 3) & 63; int kk = (tb >> 9) & 15; int mt = tb >> 13;
  int b = (mt << 4) | (l & 15);
  int c = (kk << 5) + fragK(l, e);
  uint32_t i = (uint32_t)(b * 512 + c);
  uint32_t o0, o1;
  threefry(kf[0], kf[1], 0u, i, &o0, &o1);
  Apack[(size_t)sl * 131072 + tb] = f2bf(bits2normal(o0 ^ o1));
}

// S = tanh(noise @ Ws^T + b_s) -> Sny/Snz (per (g,half), C/D-row-mapped thread
// order), and nyA (n<256 in A-frag layout, input for k_hn).
__global__ __launch_bounds__(512) void k_sgemm(const u16* __restrict__ Apack,
                                               const u16* __restrict__ Wspack,
                                               const float* __restrict__ b_s,
                                               u16* __restrict__ Sny, u16* __restrict__ Snz,
                                               u16* __restrict__ nyA) {
  int sl = blockIdx.x; int nq = blockIdx.y;
  int l = threadIdx.x & 63; int wv = threadIdx.x >> 6;
  const u16* Ab = Apack + (size_t)sl * 131072;
#pragma unroll 1
  for (int mtl = 0; mtl < 2; ++mtl) {
    int mt = 2 * wv + mtl;
    bf16x8_t af[16];
#pragma unroll
    for (int kk = 0; kk < 16; ++kk)
      af[kk] = *reinterpret_cast<const bf16x8_t*>(Ab + ((size_t)(mt * 16 + kk) * 64 + l) * 8);
#pragma unroll 1
    for (int ntl = 0; ntl < 8; ++ntl) {
      int nt = nq * 8 + ntl;
      f32x4_t acc = {0.f, 0.f, 0.f, 0.f};
#pragma unroll
      for (int kk = 0; kk < 16; ++kk) {
        bf16x8_t bfr = *reinterpret_cast<const bf16x8_t*>(Wspack + ((size_t)(nt * 16 + kk) * 64 + l) * 8);
        acc = mfma16(af[kk], bfr, acc);
      }
      int n = (nt << 4) | (l & 15);
      float bs = b_s[n];
#pragma unroll
      for (int r = 0; r < 4; ++r) {
        int m = (mt << 4) + ((l >> 4) << 2) + r;
        u16 v = f2bf(tanh_f(acc[r] + bs));
        int g = m >> 4, row = m & 15;
        if (n >= 256) {
          int h = n - 256; int hz = h >> 7;
          int tidc = ((h >> 4) & 7) * 64 + ((row >> 2) << 4) + (h & 15);
          Snz[((((size_t)sl * 16 + g) * 2 + hz) * 512 + tidc) * 4 + (row & 3)] = v;
        } else {
          int hy = n >> 7;
          int tidc = ((n >> 4) & 7) * 64 + ((row >> 2) << 4) + (n & 15);
          Sny[((((size_t)sl * 16 + g) * 2 + hy) * 512 + tidc) * 4 + (row & 3)] = v;
          int kk2 = n >> 5;
          int la = (((n & 15) >> 2) << 4) | row;
          int ea = (n & 3) | (((n >> 4) & 1) << 2);
          nyA[(((size_t)sl * 16 + g) * 8 + kk2) * 512 + la * 8 + ea] = v;
        }
      }
    }
  }
}

// HN[j] = Wh @ ny(slot j), C/D-frag layout (bf16), 48 col-tiles.
__global__ __launch_bounds__(512) void k_hn(const u16* __restrict__ nyA,
                                            const u16* __restrict__ Epack,
                                            u16* __restrict__ HNpack, int t0) {
  int j = blockIdx.x; int nq = blockIdx.y;
  int l = threadIdx.x & 63; int wv = threadIdx.x >> 6;
  int nt = nq * 8 + wv;                      // [0,48)
  if (j == 0 && t0 == 0) {
    uint2 z = {0u, 0u};
#pragma unroll 1
    for (int mt = 0; mt < 16; ++mt)
      *reinterpret_cast<uint2*>(&HNpack[(((size_t)j * 16 + mt) * 48 + nt) * 256 + l * 4]) = z;
    return;
  }
  bf16x8_t bf[8];
  const u16* bp = Epack + (size_t)(64 + nt) * 4096 + (size_t)l * 8;
#pragma unroll
  for (int kk = 0; kk < 8; ++kk)
    bf[kk] = *reinterpret_cast<const bf16x8_t*>(bp + kk * 512);
#pragma unroll 1
  for (int mt = 0; mt < 16; ++mt) {
    const u16* ap = nyA + (((size_t)j * 16 + mt) * 8) * 512 + (size_t)l * 8;
    f32x4_t acc = {0.f, 0.f, 0.f, 0.f};
#pragma unroll
    for (int kk = 0; kk < 8; ++kk)
      acc = mfma16(*reinterpret_cast<const bf16x8_t*>(ap + kk * 512), bf[kk], acc);
    union { u16 h[4]; uint2 v; } o;
#pragma unroll
    for (int r = 0; r < 4; ++r) o.h[r] = f2bf(acc[r]);
    *reinterpret_cast<uint2*>(&HNpack[(((size_t)j * 16 + mt) * 48 + nt) * 256 + l * 4]) = o.v;
  }
}

// XI[tl][g] = x @ Wi^T, C/D-frag layout (bf16), 64 col-tiles.
__global__ __launch_bounds__(512) void k_xi(const u16* __restrict__ inpPack,
                                            const u16* __restrict__ Wipack,
                                            u16* __restrict__ XIpack) {
  int tl = blockIdx.x; int nb = blockIdx.y;
  int l = threadIdx.x & 63; int wv = threadIdx.x >> 6;
  int nt = nb * 8 + wv;                      // [0,64)
  bf16x8_t bf[8];
  const u16* bp = Wipack + (size_t)nt * 4096 + (size_t)l * 8;
#pragma unroll
  for (int kk = 0; kk < 8; ++kk)
    bf[kk] = *reinterpret_cast<const bf16x8_t*>(bp + kk * 512);
#pragma unroll 1
  for (int g = 0; g < 16; ++g) {
    const u16* ap = inpPack + (size_t)(tl * 16 + g) * 4096 + (size_t)l * 8;
    f32x4_t acc = {0.f, 0.f, 0.f, 0.f};
#pragma unroll
    for (int kk = 0; kk < 8; ++kk)
      acc = mfma16(*reinterpret_cast<const bf16x8_t*>(ap + kk * 512), bf[kk], acc);
    union { u16 h[4]; uint2 v; } o;
#pragma unroll
    for (int r = 0; r < 4; ++r) o.h[r] = f2bf(acc[r]);
    *reinterpret_cast<uint2*>(&XIpack[(((size_t)tl * 16 + g) * 64 + nt) * 256 + l * 4]) = o.v;
  }
}

// ---------------------------------------------------------------------------
// Recurrence, 64 WGs x 512. wgid = role*16 + g. role 0/1 = Y(hy), 2/3 = Z(hz).
__global__ __launch_bounds__(512, 2) void k_recur(
    const float* __restrict__ dt,
    const u16* __restrict__ Epack, const u16* __restrict__ Wzpack,
    const u16* __restrict__ E2pack, const u16* __restrict__ HNpack,
    const u16* __restrict__ XIpack,
    const float* __restrict__ biasD0, const float* __restrict__ biasDn,
    const float* __restrict__ b_z, const float* __restrict__ W_dt, const float* __restrict__ b_dt,
    const u16* __restrict__ Sny, const u16* __restrict__ Snz,
    u16* __restrict__ Ypack, float* __restrict__ ystate, float* __restrict__ ypstate,
    float* __restrict__ zstate,
    uint32_t* __restrict__ yexch, uint32_t* __restrict__ yexch2,
    uint32_t* __restrict__ zexch, uint32_t* __restrict__ zexch2,
    int t0, int Tcc)
{
  extern __shared__ char lds_raw[];
  u16* wlds = (u16*)lds_raw;            // 65536 u16 (128KB): E2 tiles
  u16* buf  = wlds + 65536;             // 8192 u16: Z: y-frag dbuf; Y: [0]=y frags, [4096]=z frags
  float* sc  = (float*)(buf + 8192);    // 48
  float* scP = sc + 48;                 // 16

  const int wgid = blockIdx.x;
  const int g = wgid & 15;
  const int role = wgid >> 4;
  const bool isY = role < 2;
  const int half = role & 1;
  const int tid = threadIdx.x;
  const int l = tid & 63;
  const int wv = tid >> 6;
  const int nsteps = Tcc * 10;
  const int m2b = 4 * (l >> 4);
  const int col = half * 128 + wv * 16 + (l & 15);
  const uint32_t gb = (uint32_t)(t0 * 10);

  int wiT0, whT0, hnT0, wiT1, whT1 = -1, hnT1 = -1;
  if (isY) {
    wiT0 = half * 8 + wv;       whT0 = 64 + wiT0;  hnT0 = wiT0;
    wiT1 = 32 + half * 8 + wv;
  } else {
    wiT0 = 16 + half * 8 + wv;  whT0 = 64 + wiT0;  hnT0 = wiT0;
    wiT1 = 48 + half * 8 + wv;  whT1 = 96 + half * 8 + wv;  hnT1 = 32 + half * 8 + wv;
  }
  float b0d0 = biasD0[wiT0 * 16 + (l & 15)], b0dn = biasDn[wiT0 * 16 + (l & 15)];
  float b1d0 = biasD0[wiT1 * 16 + (l & 15)], b1dn = biasDn[wiT1 * 16 + (l & 15)];

  // ---- preload E2 weight tiles into LDS ----
  for (int i = tid; i < 8192; i += 512) {
    int t = i >> 9; int o = (i & 511) << 3;
    int gt;
    if (isY) gt = (t < 8) ? (half * 8 + t) : (32 + half * 8 + (t - 8));
    else     gt = (t < 8) ? (16 + half * 8 + t) : (48 + half * 8 + (t - 8));
    *reinterpret_cast<uint4*>(wlds + t * 4096 + o) =
        *reinterpret_cast<const uint4*>(E2pack + (size_t)gt * 4096 + o);
  }

  float zc[4], yc[4], ylast[4];
  bf16x8_t wzf[8];
  float bzr = 0.f;
  float wdt0 = W_dt[0], wdt1 = W_dt[1], bdt0 = b_dt[0], bdt1 = b_dt[1];

  if (isY) {
    bzr = b_z[col];
#pragma unroll
    for (int kk = 0; kk < 8; ++kk)
      wzf[kk] = *reinterpret_cast<const bf16x8_t*>(
          Wzpack + (size_t)(half * 8 + wv) * 4096 + (size_t)kk * 512 + (size_t)l * 8);
    u16 v[4];
#pragma unroll
    for (int r = 0; r < 4; ++r) {
      int m2 = m2b + r;
      yc[r] = (t0 == 0) ? 0.f : ystate[(size_t)(g * 16 + m2) * 256 + col];
      ylast[r] = 0.f;
      float vv = (t0 == 0) ? 0.f : ypstate[(size_t)(g * 16 + m2) * 256 + col];
      v[r] = f2bf(vv);
    }
    int base = fslot(col, m2b);
    buf[base] = v[0]; buf[base + 8] = v[1]; buf[base + 16] = v[2]; buf[base + 24] = v[3];
    uint32_t w0 = (uint32_t)v[0] | ((uint32_t)v[1] << 16);
    uint32_t w1 = (uint32_t)v[2] | ((uint32_t)v[3] << 16);
    size_t so = ((size_t)g * 1024 + half * 512 + tid) * 4;     // buffer 0
    publish(yexch + so, yexch2 + so, w0, w1, gb + 1u);
  } else {
#pragma unroll
    for (int r = 0; r < 4; ++r)
      zc[r] = (t0 == 0) ? 0.f : zstate[(size_t)(g * 16 + m2b + r) * 256 + col];
  }

  if (!isY) {
    // =============== Z loop: 1 barrier/step ===============
    for (int s = 0; s < nsteps; ++s) {
      int d = s % 10;
      uint2 nsv = *reinterpret_cast<const uint2*>(
          Snz + ((((size_t)(s + 1) * 16 + g) * 2 + half) * 512 + tid) * 4);
      size_t HNs = ((size_t)s * 16 + g) * 48;
      uint2 hv0 = *reinterpret_cast<const uint2*>(HNpack + (HNs + hnT0) * 256 + l * 4);
      uint2 hv1 = *reinterpret_cast<const uint2*>(HNpack + (HNs + hnT1) * 256 + l * 4);
      uint2 xi0 = {0u, 0u}, xi1 = {0u, 0u};
      if (d == 0) {
        int tl = s / 10;
        size_t XIs = ((size_t)tl * 16 + g) * 64;
        xi0 = *reinterpret_cast<const uint2*>(XIpack + (XIs + wiT0) * 256 + l * 4);
        xi1 = *reinterpret_cast<const uint2*>(XIpack + (XIs + wiT1) * 256 + l * 4);
        if (tid < 16) {
          float dl = dt[(size_t)(t0 + tl) * 256 + g * 16 + tid] * 0.1f;
          sc[tid] = dl;
          sc[16 + tid] = sigm(fmaf(dl, wdt0, bdt0));
          sc[32 + tid] = sigm(fmaf(dl, wdt1, bdt1));
          int tp = t0 + tl - 1; if (tp < 0) tp = 0;
          scP[tid] = dt[(size_t)tp * 256 + g * 16 + tid] * 0.1f;
        }
      }
      uint32_t seq = gb + (uint32_t)s + 1u;
      // poll full y; scatter into parity buffer
      size_t bo = (((size_t)(s & 1) * 16 + g) * 1024 + 2 * tid) * 4;
      u32x4_t pa, pb;
      pollpair_dual(yexch2 + bo, yexch + bo, seq, &pa, &pb);
      u16* yb = buf + (s & 1) * 4096;
      scatter2(yb, 2 * tid, pa);
      scatter2(yb, 2 * tid + 1, pb);
      __syncthreads();
      // ---- A ----
      bf16x8_t ay[8];
#pragma unroll
      for (int kk = 0; kk < 8; ++kk)
        ay[kk] = *reinterpret_cast<const bf16x8_t*>(yb + kk * 512 + l * 8);
      float scv[4];
#pragma unroll
      for (int r = 0; r < 4; ++r) scv[r] = (d == 0 ? scP[m2b + r] : sc[m2b + r]);
      f32x4_t a0 = {0.f, 0.f, 0.f, 0.f}, a1 = {0.f, 0.f, 0.f, 0.f};
      if (d == 0) {
        const u16* hp0 = Epack + (size_t)whT0 * 4096 + (size_t)l * 8;
        const u16* hp1 = Epack + (size_t)whT1 * 4096 + (size_t)l * 8;
#pragma unroll
        for (int kk = 0; kk < 8; ++kk)
          a0 = mfma16(ay[kk], *reinterpret_cast<const bf16x8_t*>(hp0 + kk * 512), a0);
#pragma unroll
        for (int kk = 0; kk < 8; ++kk)
          a1 = mfma16(ay[kk], *reinterpret_cast<const bf16x8_t*>(hp1 + kk * 512), a1);
      } else {
        const u16* w0p = wlds + wv * 4096 + l * 8;
        const u16* w1p = wlds + (8 + wv) * 4096 + l * 8;
#pragma unroll
        for (int kk = 0; kk < 8; ++kk)
          a0 = mfma16(ay[kk], *reinterpret_cast<const bf16x8_t*>(w0p + kk * 512), a0);
#pragma unroll
        for (int kk = 0; kk < 8; ++kk)
          a1 = mfma16(ay[kk], *reinterpret_cast<const bf16x8_t*>(w1p + kk * 512), a1);
      }
      const u16* h0 = (const u16*)&hv0; const u16* h1 = (const u16*)&hv1;
      const u16* x0 = (const u16*)&xi0; const u16* x1 = (const u16*)&xi1;
      // ---- B: z update, publish direct ----
      const u16* nzp = (const u16*)&nsv;
      u16 zv[4];
#pragma unroll
      for (int r = 0; r < 4; ++r) {
        int m2 = m2b + r;
        float r0 = a0[r] + (d == 0 ? (b0d0 + bf2f(x0[r])) : b0dn) + scv[r] * bf2f(h0[r]);
        float r1 = a1[r] + (d == 0 ? (b1d0 + bf2f(x1[r])) : b1dn) + scv[r] * bf2f(h1[r]);
        float ms = sc[32 + m2] * sigm(r0);
        float zn = (1.0f - ms) * zc[r] + ms * tanh_f(r1);
        zv[r] = f2bf(zn);
        zc[r] = fmaf(bf2f(nzp[r]), sc[m2], zn);
      }
      uint32_t w0z = (uint32_t)zv[0] | ((uint32_t)zv[1] << 16);
      uint32_t w1z = (uint32_t)zv[2] | ((uint32_t)zv[3] << 16);
      size_t so = (((size_t)(s & 1) * 16 + g) * 1024 + half * 512 + tid) * 4;
      publish(zexch + so, zexch2 + so, w0z, w1z, seq);
    }
#pragma unroll
    for (int r = 0; r < 4; ++r)
      zstate[(size_t)(g * 16 + m2b + r) * 256 + col] = zc[r];
  } else {
    // =============== Y loop: 2 barriers/step ===============
    for (int s = 0; s < nsteps; ++s) {
      int d = s % 10, tl = s / 10;
      uint2 nsv = *reinterpret_cast<const uint2*>(
          Sny + ((((size_t)(s + 1) * 16 + g) * 2 + half) * 512 + tid) * 4);
      size_t HNs = ((size_t)s * 16 + g) * 48;
      uint2 hv0 = *reinterpret_cast<const uint2*>(HNpack + (HNs + hnT0) * 256 + l * 4);
      uint2 xi0 = {0u, 0u}, xi1 = {0u, 0u};
      if (d == 0) {
        size_t XIs = ((size_t)tl * 16 + g) * 64;
        xi0 = *reinterpret_cast<const uint2*>(XIpack + (XIs + wiT0) * 256 + l * 4);
        xi1 = *reinterpret_cast<const uint2*>(XIpack + (XIs + wiT1) * 256 + l * 4);
        if (tid < 16) {
          float dl = dt[(size_t)(t0 + tl) * 256 + g * 16 + tid] * 0.1f;
          sc[tid] = dl;
          sc[16 + tid] = sigm(fmaf(dl, wdt0, bdt0));
          sc[32 + tid] = sigm(fmaf(dl, wdt1, bdt1));
          int tp = t0 + tl - 1; if (tp < 0) tp = 0;
          scP[tid] = dt[(size_t)tp * 256 + g * 16 + tid] * 0.1f;
        }
      }
      uint32_t seq = gb + (uint32_t)s + 1u;
      // poll other y half (self half written during previous C)
      {
        int j = ((1 ^ half) * 512 + tid);
        size_t bo = (((size_t)(s & 1) * 16 + g) * 1024 + j) * 4;
        u32x4_t pa;
        poll1_dual(yexch2 + bo, yexch + bo, seq, &pa);
        scatter2(buf, j, pa);
      }
      __syncthreads();                                  // BAR_1
      // ---- A ----
      f32x4_t r0v, r1v;
      {
        bf16x8_t ay[8];
#pragma unroll
        for (int kk = 0; kk < 8; ++kk)
          ay[kk] = *reinterpret_cast<const bf16x8_t*>(buf + kk * 512 + l * 8);
        float scv[4];
#pragma unroll
        for (int r = 0; r < 4; ++r) scv[r] = (d == 0 ? scP[m2b + r] : sc[m2b + r]);
        f32x4_t a0 = {0.f, 0.f, 0.f, 0.f}, a1 = {0.f, 0.f, 0.f, 0.f};
        if (d == 0) {
          const u16* hp0 = Epack + (size_t)whT0 * 4096 + (size_t)l * 8;
#pragma unroll
          for (int kk = 0; kk < 8; ++kk)
            a0 = mfma16(ay[kk], *reinterpret_cast<const bf16x8_t*>(hp0 + kk * 512), a0);
        } else {
          const u16* w0p = wlds + wv * 4096 + l * 8;
          const u16* w1p = wlds + (8 + wv) * 4096 + l * 8;
#pragma unroll
          for (int kk = 0; kk < 8; ++kk)
            a0 = mfma16(ay[kk], *reinterpret_cast<const bf16x8_t*>(w0p + kk * 512), a0);
#pragma unroll
          for (int kk = 0; kk < 8; ++kk)
            a1 = mfma16(ay[kk], *reinterpret_cast<const bf16x8_t*>(w1p + kk * 512), a1);
        }
        const u16* h0 = (const u16*)&hv0;
        const u16* x0 = (const u16*)&xi0; const u16* x1 = (const u16*)&xi1;
#pragma unroll
        for (int r = 0; r < 4; ++r) {
          r0v[r] = a0[r] + (d == 0 ? (b0d0 + bf2f(x0[r])) : b0dn) + scv[r] * bf2f(h0[r]);
          r1v[r] = (d == 0) ? (b1d0 + bf2f(x1[r])) : (a1[r] + b1dn);
        }
      }
      // poll z (full), scatter
      {
        size_t bo = (((size_t)(s & 1) * 16 + g) * 1024 + 2 * tid) * 4;
        u32x4_t qa, qb;
        pollpair_dual(zexch2 + bo, zexch + bo, seq, &qa, &qb);
        u16* zb = buf + 4096;
        scatter2(zb, 2 * tid, qa);
        scatter2(zb, 2 * tid + 1, qb);
      }
      __syncthreads();                                  // BAR_2
      // ---- C ----
      bf16x8_t zfr[8];
#pragma unroll
      for (int kk = 0; kk < 8; ++kk)
        zfr[kk] = *reinterpret_cast<const bf16x8_t*>(buf + 4096 + kk * 512 + l * 8);
      f32x4_t acc = {0.f, 0.f, 0.f, 0.f};
#pragma unroll
      for (int kk = 0; kk < 8; ++kk) acc = mfma16(zfr[kk], wzf[kk], acc);
      const u16* nyp = (const u16*)&nsv;
      u16 yv[4], pv[4];
      int base = fslot(col, m2b);
#pragma unroll
      for (int r = 0; r < 4; ++r) {
        int m2 = m2b + r;
        float u = acc[r] + bzr + r1v[r];
        float msb = sc[16 + m2] * sigm(r0v[r]);
        float yn = (1.0f - msb) * yc[r] + msb * tanh_f(u);
        float ypn = fmaf(bf2f(nyp[r]), sc[m2], yn);
        yc[r] = ypn; ylast[r] = yn;
        yv[r] = f2bf(yn); pv[r] = f2bf(ypn);
        buf[base + 8 * r] = yv[r];                      // self-half y(s+1)
      }
      uint32_t wy0 = (uint32_t)yv[0] | ((uint32_t)yv[1] << 16);
      uint32_t wy1 = (uint32_t)yv[2] | ((uint32_t)yv[3] << 16);
      size_t so = (((size_t)((s + 1) & 1) * 16 + g) * 1024 + half * 512 + tid) * 4;
      publish(yexch + so, yexch2 + so, wy0, wy1, gb + (uint32_t)s + 2u);
      if (d == 9) {
        uint2 pp = {(uint32_t)pv[0] | ((uint32_t)pv[1] << 16),
                    (uint32_t)pv[2] | ((uint32_t)pv[3] << 16)};
        *reinterpret_cast<uint2*>(Ypack + (size_t)(tl * 16 + g) * 4096 + (half * 512 + tid) * 4) = pp;
      }
    }
#pragma unroll
    for (int r = 0; r < 4; ++r) {
      int m2 = m2b + r;
      ystate[(size_t)(g * 16 + m2) * 256 + col] = yc[r];
      ypstate[(size_t)(g * 16 + m2) * 256 + col] = ylast[r];
    }
  }
}

// out[t] = Y[t] @ W_c^T + b_c.  Ypack is C/D-order; transpose via LDS here.
__global__ __launch_bounds__(512) void k_out(const u16* __restrict__ Ypack, const u16* __restrict__ Wcpack,
                                             const float* __restrict__ b_c, float* __restrict__ out, int t0) {
  __shared__ u16 yl[4 * 4096];
  int tl = blockIdx.x; int mh = blockIdx.y;
  int tid = threadIdx.x; int l = tid & 63; int wv = tid >> 6;
  for (int i = tid; i < 4096; i += 512) {
    int pg = i >> 10; int j = i & 1023;
    uint2 v = *reinterpret_cast<const uint2*>(
        Ypack + ((size_t)(tl * 16 + mh * 4 + pg)) * 4096 + (size_t)j * 4);
    int wvp = (j >> 6) & 7, lp = j & 63, hf = j >> 9;
    int colp = hf * 128 + wvp * 16 + (lp & 15);
    int mb = 4 * (lp >> 4);
    int base = pg * 4096 + fslot(colp, mb);
    yl[base] = (u16)(v.x & 0xffffu);
    yl[base + 8] = (u16)(v.x >> 16);
    yl[base + 16] = (u16)(v.y & 0xffffu);
    yl[base + 24] = (u16)(v.y >> 16);
  }
  __syncthreads();
  int gl = wv >> 1; int nh = wv & 1;
  int mt = mh * 4 + gl;
  bf16x8_t af[8];
#pragma unroll
  for (int kk = 0; kk < 8; ++kk)
    af[kk] = *reinterpret_cast<const bf16x8_t*>(yl + gl * 4096 + kk * 512 + l * 8);
#pragma unroll 1
  for (int ntl = 0; ntl < 8; ++ntl) {
    int nt = nh * 8 + ntl;
    f32x4_t acc = {0.f, 0.f, 0.f, 0.f};
    const u16* bp = Wcpack + ((size_t)nt * 8 * 64 + l) * 8;
#pragma unroll
    for (int kk = 0; kk < 8; ++kk) {
      bf16x8_t bfr = *reinterpret_cast<const bf16x8_t*>(bp + kk * 512);
      acc = mfma16(af[kk], bfr, acc);
    }
    int n = (nt << 4) | (l & 15);
    float bc = b_c[n];
#pragma unroll
    for (int r = 0; r < 4; ++r) {
      int m = (mt << 4) + ((l >> 4) << 2) + r;
      out[((size_t)(t0 + tl) * 256 + m) * 256 + n] = acc[r] + bc;
    }
  }
}

// ---------------------------------------------------------------------------
extern "C" void kernel_launch(void* const* d_in, const int* in_sizes, int n_in,
                              void* d_out, int out_size, void* d_ws, size_t ws_size,
                              hipStream_t stream) {
  const float* input = (const float*)d_in[0];
  const float* dt    = (const float*)d_in[1];
  const float* W_i   = (const float*)d_in[2];
  const float* b_i   = (const float*)d_in[3];
  const float* W_h   = (const float*)d_in[4];
  const float* b_h   = (const float*)d_in[5];
  const float* W_z   = (const float*)d_in[6];
  const float* b_z   = (const float*)d_in[7];
  const float* W_dt  = (const float*)d_in[8];
  const float* b_dt  = (const float*)d_in[9];
  const float* W_c   = (const float*)d_in[10];
  const float* b_c   = (const float*)d_in[11];
  const float* W_s   = (const float*)d_in[12];
  const float* b_s   = (const float*)d_in[13];
  float* out = (float*)d_out;

  char* ws = (char*)d_ws;
  size_t off = 0;
  auto alloc = [&](size_t bytes) -> char* {
    char* p = ws + off; off = (off + bytes + 255) & ~(size_t)255; return p;
  };
  u16* Epack   = (u16*)alloc((size_t)112 * 4096 * 2);
  u16* Wipack  = (u16*)alloc((size_t)64 * 4096 * 2);
  u16* Wzpack  = (u16*)alloc((size_t)16 * 4096 * 2);
  u16* Wcpack  = (u16*)alloc((size_t)16 * 4096 * 2);
  u16* Wspack  = (u16*)alloc((size_t)32 * 16 * 512 * 2);
  u16* E2pack  = (u16*)alloc((size_t)64 * 4096 * 2);
  float* bip   = (float*)alloc(1024 * 4);
  float* biasD0= (float*)alloc(1024 * 4);
  float* biasDn= (float*)alloc(1024 * 4);
  float* Wic   = (float*)alloc((size_t)1024 * 256 * 4);
  float* ystate= (float*)alloc((size_t)256 * 256 * 4);
  float* ypstate=(float*)alloc((size_t)256 * 256 * 4);
  float* zstate= (float*)alloc((size_t)256 * 256 * 4);
  uint32_t* yexch  = (uint32_t*)alloc((size_t)2 * 16 * 1024 * 16);
  uint32_t* yexch2 = (uint32_t*)alloc((size_t)2 * 16 * 1024 * 16);
  uint32_t* zexch  = (uint32_t*)alloc((size_t)2 * 16 * 1024 * 16);
  uint32_t* zexch2 = (uint32_t*)alloc((size_t)2 * 16 * 1024 * 16);
  size_t fixed = off;
  size_t per_slot = (size_t)131072 * 2 + 65536 * 2 + 65536 * 2 + 65536 * 2;
  size_t per_t = 10 * per_slot + (size_t)10 * 196608 * 2 + 131072 + 131072 + 524288;
  int Tc = 1;
  if (ws_size > fixed + per_t + per_slot) {
    size_t n = (ws_size - fixed - per_slot) / per_t;
    Tc = (n > 128) ? 128 : (int)n;
  }
  if (Tc < 1) Tc = 1;
  int maxslots = Tc * 10 + 1;
  u16* Apack   = (u16*)alloc((size_t)maxslots * 131072 * 2);
  u16* Sny     = (u16*)alloc((size_t)maxslots * 65536 * 2);
  u16* Snz     = (u16*)alloc((size_t)maxslots * 65536 * 2);
  u16* nyA     = (u16*)alloc((size_t)maxslots * 65536 * 2);
  u16* HNpack  = (u16*)alloc((size_t)(Tc * 10) * 196608 * 2);
  u16* inpPack = (u16*)alloc((size_t)Tc * 16 * 8 * 512 * 2);
  u16* XIpack  = (u16*)alloc((size_t)Tc * 524288);
  u16* Ypack   = (u16*)alloc((size_t)Tc * 16 * 8 * 512 * 2);

  (void)hipFuncSetAttribute((const void*)k_recur, hipFuncAttributeMaxDynamicSharedMemorySize,
                            R_LDS_BYTES);

  k_prep<<<1024, 256, 0, stream>>>(W_i, W_c, b_i, b_c, Wic, bip);
  k_bias<<<4, 256, 0, stream>>>(b_i, bip, b_h, biasD0, biasDn);
  k_packw<<<(112 * 8 * 64) / 256, 256, 0, stream>>>(Wic, 1024, W_h, Epack, 1792, 256);
  k_packw<<<(64 * 8 * 64) / 256, 256, 0, stream>>>(W_i, 1024, (const float*)nullptr, Wipack, 1024, 256);
  k_packw<<<(16 * 8 * 64) / 256, 256, 0, stream>>>(W_z, 256, (const float*)nullptr, Wzpack, 256, 256);
  k_packw<<<(16 * 8 * 64) / 256, 256, 0, stream>>>(W_c, 256, (const float*)nullptr, Wcpack, 256, 256);
  k_packw<<<(32 * 16 * 64) / 256, 256, 0, stream>>>(W_s, 512, (const float*)nullptr, Wspack, 512, 512);
  k_packe2<<<128, 256, 0, stream>>>(Wic, W_h, E2pack);

  for (int t0 = 0; t0 < 128; t0 += Tc) {
    int Tcc = (128 - t0 < Tc) ? (128 - t0) : Tc;
    int nsteps = Tcc * 10;
    int slots = nsteps + 1;
    k_gen<<<slots * 128, 1024, 0, stream>>>(Apack, t0 * 10 - 1);
    dim3 g2(slots, 4);
    k_sgemm<<<g2, 512, 0, stream>>>(Apack, Wspack, b_s, Sny, Snz, nyA);
    dim3 g3(nsteps, 6);
    k_hn<<<g3, 512, 0, stream>>>(nyA, Epack, HNpack, t0);
    int totalA = Tcc * 16 * 8 * 64;
    k_packa<<<(totalA + 255) / 256, 256, 0, stream>>>(input, t0, Tcc, inpPack);
    dim3 gx(Tcc, 8);
    k_xi<<<gx, 512, 0, stream>>>(inpPack, Wipack, XIpack);
    k_recur<<<64, 512, R_LDS_BYTES, stream>>>(dt, Epack, Wzpack, E2pack, HNpack, XIpack,
                                              biasD0, biasDn, b_z, W_dt, b_dt, Sny, Snz,
                                              Ypack, ystate, ypstate, zstate,
                                              yexch, yexch2, zexch, zexch2, t0, Tcc);
    dim3 ge(Tcc, 4);
    k_out<<<ge, 512, 0, stream>>>(Ypack, Wcpack, b_c, out, t0);
  }
}